// Round 9
// baseline (166.910 us; speedup 1.0000x reference)
//
#include <hip/hip_runtime.h>
#include <hip/hip_bf16.h>

// Causal attention, S=4096, d=1024, fp32 in/out.
// bf16 MFMA for projections and PV; fp8 e4m3 MFMA (BK=128B) for scores only.
//
// Round-19: RESUBMIT of round-18 (container failed twice pre-bench; same
// infra mode as r14/r15 where the BYTE-IDENTICAL kernel then passed).
// Static re-audit of the new f32-sb tile found no hazard: uniform barriers
// (wm-guard covers writes only), bounce bounds <32KB, swizzle involution
// verified, non-empty split ranges, VGPR fits (256,4). One retry; if it
// fails again, attribution flips to code and k_pv reverts to r17.
//
// Round-18: k_pv -> single-buffer 33KB tile @ 4 blocks/CU (r17's proven
// trade). Grid c=16 / 640 blocks (r12 mapping -> split boundaries bit-
// identical to a config measured at absmax 0.02734375). fp32 C bounce in
// two 64-row halves. Partials 72 groups; k_reduce r12 mapping.
//
// Workspace (256 MiB):
//   [0,8M)    x_bf  [4096,1024] bf16
//   [8M,12M)  Wqk   [2048,1024] bf16 (Wq rows 0..1023, Wk rows 1024..2047)
//   [12M,14M) Wv_bf [1024,1024] bf16
//   [14M,22M) QK    [4096,2048] fp8  (Q cols 0..1023, K cols 1024..2047)
//   [22M,30M) Vt    [1024,4096] bf16 (V^T, computed directly as Wv @ x^T)
//   [30M,62M) P~    [4096,4096] bf16 (exp(s/32), masked, unnormalized)
//   [62M,62.5M) rowsum_part [4096][32] fp32 (slot bn; dead slots zeroed)
//   [64M,100M) PV fp32 partials (72 multi-split groups x 8 bn x 64 KB)

typedef __bf16 bf16_t;
typedef __bf16 bf16x4v __attribute__((ext_vector_type(4)));
typedef __bf16 bf16x8 __attribute__((ext_vector_type(8)));
typedef float f32x4 __attribute__((ext_vector_type(4)));
typedef unsigned char u8;
typedef long long i64_t;

#define AS1 __attribute__((address_space(1)))
#define AS3 __attribute__((address_space(3)))
#define WAIT_VMCNT(N) asm volatile("s_waitcnt vmcnt(" #N ")" ::: "memory")
#define BARRIER_RAW() asm volatile("s_barrier" ::: "memory")

__device__ __forceinline__ void async_copy16(const void* g, void* l) {
    // 16B/lane direct global->LDS; LDS dest = wave-uniform base + lane*16
    __builtin_amdgcn_global_load_lds((AS1 void*)(g), (AS3 void*)(l), 16, 0, 0);
}

__device__ __forceinline__ u8 f32_to_fp8(float v) {
    // OCP e4m3 on gfx950 (HW conversion); layout validated in round 6
    return (u8)(__builtin_amdgcn_cvt_pk_fp8_f32(v, v, 0, false) & 0xff);
}

__device__ __forceinline__ void store_conv(float* p, float v) { *p = v; }
__device__ __forceinline__ void store_conv(bf16_t* p, float v) { *p = (bf16_t)v; }
__device__ __forceinline__ void store_conv(u8* p, float v) { *p = f32_to_fp8(v); }

// Sum of 32 consecutive floats (8x float4), for 1/rowsum computation.
__device__ __forceinline__ float sum32(const float* p) {
    const f32x4* v = (const f32x4*)p;
    float s = 0.f;
#pragma unroll
    for (int u = 0; u < 8; ++u) {
        f32x4 a = v[u];
        s += a[0] + a[1] + a[2] + a[3];
    }
    return s;
}

// ---------------- bf16 tile: BM=128, BN=128, BK=64 (r12, dbuf 64KB) -------
// Double-buffered staging: A bufs [0,16K),[16K,32K); B bufs [32K,48K),[48K,64K).
// XOR-swizzled LDS (16B chunk b of row r holds k-chunk b^(r&7)).
// Counted-vmcnt 2-barrier K-loop. Epilogue: LDS-bounce -> 16B coalesced stores.
// EPI 0: C = v*alpha (used by k_qkv only here)
template <int EPI, typename OutT>
__device__ __forceinline__ void gemm_tile_bf16(const bf16_t* __restrict__ A, int lda,
                                               const bf16_t* __restrict__ B, int ldb,
                                               OutT* __restrict__ C, int ldc,
                                               int kb0, int kb1, float alpha,
                                               char* __restrict__ smem,
                                               const float* __restrict__ inv) {
    constexpr int BK = 64;
    bf16_t* As = (bf16_t*)smem;            // 2 x 8192 elems (16KB each)
    bf16_t* Bs = (bf16_t*)(smem + 32768);  // 2 x 8192 elems
    const int tid = threadIdx.x;
    const int lane = tid & 63, wave = tid >> 6;
    const int wm = wave >> 1, wn = wave & 1;
    const int q = lane >> 4, l16 = lane & 15;

    f32x4 acc[4][4] = {};

    const bf16_t* aSrc[4];
    const bf16_t* bSrc[4];
    int ldsOff[4];
#pragma unroll
    for (int it = 0; it < 4; ++it) {
        int c = it * 256 + tid;
        int r = c >> 3, b = c & 7;
        int sb = b ^ (r & 7);
        aSrc[it] = A + (size_t)r * lda + sb * 8;
        bSrc[it] = B + (size_t)r * ldb + sb * 8;
        ldsOff[it] = c * 8;
    }

    // prologue: stage first K-step into buffer 0 (8 loads in flight)
    {
        const int k0 = kb0 * BK;
#pragma unroll
        for (int it = 0; it < 4; ++it) async_copy16(aSrc[it] + k0, &As[ldsOff[it]]);
#pragma unroll
        for (int it = 0; it < 4; ++it) async_copy16(bSrc[it] + k0, &Bs[ldsOff[it]]);
    }

    int cur = 0;
    for (int kb = kb0; kb < kb1; ++kb) {
        if (kb + 1 < kb1) {  // prefetch next K-step into alternate buffer
            const int k0 = (kb + 1) * BK;
            const int boff = (cur ^ 1) * 8192;
#pragma unroll
            for (int it = 0; it < 4; ++it) async_copy16(aSrc[it] + k0, &As[boff + ldsOff[it]]);
#pragma unroll
            for (int it = 0; it < 4; ++it) async_copy16(bSrc[it] + k0, &Bs[boff + ldsOff[it]]);
            WAIT_VMCNT(8);   // tile-kb loads (8 oldest) retired; kb+1 in flight
        } else {
            WAIT_VMCNT(0);   // tail: drain everything
        }
        __builtin_amdgcn_sched_barrier(0);
        BARRIER_RAW();       // all waves' tile-kb loads landed
        const bf16_t* Ab = As + cur * 8192;
        const bf16_t* Bb = Bs + cur * 8192;
        __builtin_amdgcn_s_setprio(1);
#pragma unroll
        for (int k2 = 0; k2 < 2; ++k2) {
            bf16x8 af[4], bfr[4];
#pragma unroll
            for (int mt = 0; mt < 4; ++mt) {
                int m = wm * 64 + mt * 16 + l16;
                int blk = (k2 * 4 + q) ^ (m & 7);
                af[mt] = *(const bf16x8*)&Ab[m * BK + blk * 8];
            }
#pragma unroll
            for (int nt = 0; nt < 4; ++nt) {
                int nn = wn * 64 + nt * 16 + l16;
                int blk = (k2 * 4 + q) ^ (nn & 7);
                bfr[nt] = *(const bf16x8*)&Bb[nn * BK + blk * 8];
            }
#pragma unroll
            for (int mt = 0; mt < 4; ++mt)
#pragma unroll
                for (int nt = 0; nt < 4; ++nt)
                    acc[mt][nt] = __builtin_amdgcn_mfma_f32_16x16x32_bf16(
                        af[mt], bfr[nt], acc[mt][nt], 0, 0, 0);
        }
        __builtin_amdgcn_s_setprio(0);
        BARRIER_RAW();       // reads of buf done -> next iter may overwrite
        cur ^= 1;
    }

    // Epilogue: bounce C tile (128x128 OutT) through dead staging LDS.
    // C/D layout: col = lane&15, row = (lane>>4)*4 + reg.
    constexpr int S = (int)sizeof(OutT);
    constexpr int RB = 128 * S;  // bytes per tile row
    const int row0 = wm * 64, col0 = wn * 64;
#pragma unroll
    for (int mt = 0; mt < 4; ++mt)
#pragma unroll
        for (int nt = 0; nt < 4; ++nt)
#pragma unroll
            for (int r = 0; r < 4; ++r) {
                int lr = row0 + mt * 16 + q * 4 + r;
                int lc = col0 + nt * 16 + l16;
                float v = acc[mt][nt][r];
                v = (EPI == 2) ? v * inv[lr] : v * alpha;
                int cb = (lc * S) >> 4;
                int sw = cb ^ ((lr >> 2) & 7);
                store_conv((OutT*)(smem + lr * RB + (sw << 4) + ((lc * S) & 15)), v);
            }
    __syncthreads();
    // stream out: 16B/thread/pass, fully coalesced (4 threads = one 64B line)
#pragma unroll
    for (int p = 0; p < 4 * S; ++p) {
        int g = p * 4096 + tid * 16;  // linear byte index in tile
        int r = g / RB;
        int wb = g & (RB - 1);
        int sc = (wb >> 4) ^ ((r >> 2) & 7);
        f32x4 val = *(const f32x4*)(smem + r * RB + (sc << 4));
        *(f32x4*)((char*)C + (size_t)r * ((size_t)ldc * S) + wb) = val;
    }
}

// ---------------- bf16 tile, single-buffer 32KB (m97 structure) -----------
// As [0,16K), Bs [16K,32K). Per iter: stage 8 loads -> __syncthreads ->
// ds_read + 32 MFMA -> __syncthreads. 4 blocks/CU; cross-block wave overlap
// hides the drain (m97/m114). Epilogue: 32KB LDS bounce (bf16 out).
__device__ __forceinline__ void gemm_tile_bf16_sb(const bf16_t* __restrict__ A, int lda,
                                                  const bf16_t* __restrict__ B, int ldb,
                                                  bf16_t* __restrict__ C, int ldc,
                                                  int kb1, char* __restrict__ smem) {
    constexpr int BK = 64;
    bf16_t* As = (bf16_t*)smem;            // 8192 elems (16KB)
    bf16_t* Bs = (bf16_t*)(smem + 16384);  // 8192 elems
    const int tid = threadIdx.x;
    const int lane = tid & 63, wave = tid >> 6;
    const int wm = wave >> 1, wn = wave & 1;
    const int q = lane >> 4, l16 = lane & 15;

    f32x4 acc[4][4] = {};

    const bf16_t* aSrc[4];
    const bf16_t* bSrc[4];
    int ldsOff[4];
#pragma unroll
    for (int it = 0; it < 4; ++it) {
        int c = it * 256 + tid;
        int r = c >> 3, b = c & 7;
        int sb = b ^ (r & 7);
        aSrc[it] = A + (size_t)r * lda + sb * 8;
        bSrc[it] = B + (size_t)r * ldb + sb * 8;
        ldsOff[it] = c * 8;
    }

    for (int kb = 0; kb < kb1; ++kb) {
        const int k0 = kb * BK;
#pragma unroll
        for (int it = 0; it < 4; ++it) async_copy16(aSrc[it] + k0, &As[ldsOff[it]]);
#pragma unroll
        for (int it = 0; it < 4; ++it) async_copy16(bSrc[it] + k0, &Bs[ldsOff[it]]);
        __syncthreads();
        __builtin_amdgcn_s_setprio(1);
#pragma unroll
        for (int k2 = 0; k2 < 2; ++k2) {
            bf16x8 af[4], bfr[4];
#pragma unroll
            for (int mt = 0; mt < 4; ++mt) {
                int m = wm * 64 + mt * 16 + l16;
                int blk = (k2 * 4 + q) ^ (m & 7);
                af[mt] = *(const bf16x8*)&As[m * BK + blk * 8];
            }
#pragma unroll
            for (int nt = 0; nt < 4; ++nt) {
                int nn = wn * 64 + nt * 16 + l16;
                int blk = (k2 * 4 + q) ^ (nn & 7);
                bfr[nt] = *(const bf16x8*)&Bs[nn * BK + blk * 8];
            }
#pragma unroll
            for (int mt = 0; mt < 4; ++mt)
#pragma unroll
                for (int nt = 0; nt < 4; ++nt)
                    acc[mt][nt] = __builtin_amdgcn_mfma_f32_16x16x32_bf16(
                        af[mt], bfr[nt], acc[mt][nt], 0, 0, 0);
        }
        __builtin_amdgcn_s_setprio(0);
        __syncthreads();  // reads done -> next stage may overwrite
    }

    // Epilogue: bounce C tile (128x128 bf16, 32KB) through staging LDS.
    constexpr int RB = 256;
    const int row0 = wm * 64, col0 = wn * 64;
#pragma unroll
    for (int mt = 0; mt < 4; ++mt)
#pragma unroll
        for (int nt = 0; nt < 4; ++nt)
#pragma unroll
            for (int r = 0; r < 4; ++r) {
                int lr = row0 + mt * 16 + q * 4 + r;
                int lc = col0 + nt * 16 + l16;
                int cb = (lc * 2) >> 4;
                int sw = cb ^ ((lr >> 2) & 7);
                *(bf16_t*)(smem + lr * RB + (sw << 4) + ((lc * 2) & 15)) =
                    (bf16_t)acc[mt][nt][r];
            }
    __syncthreads();
#pragma unroll
    for (int p = 0; p < 8; ++p) {
        int g = p * 4096 + tid * 16;
        int r = g >> 8, wb = g & 255;
        int sc = (wb >> 4) ^ ((r >> 2) & 7);
        f32x4 val = *(const f32x4*)(smem + r * RB + (sc << 4));
        *(f32x4*)((char*)C + (size_t)r * ((size_t)ldc * 2) + wb) = val;
    }
}

// ---------------- f32-out tile, single-buffer 32KB (k_pv) -----------------
// Same K-loop as gemm_tile_bf16_sb (accumulation order identical to the r12
// dbuf tile: kb ascending, k2 0..1, mt/nt order). fp32 C tile = 64KB, so the
// bounce runs in two 64-row halves (32KB each; wave wm owns half wm).
// EPI 0: C = v (partials) | EPI 2: C = v * inv[row] (direct out).
template <int EPI>
__device__ __forceinline__ void gemm_tile_f32_sb(const bf16_t* __restrict__ A, int lda,
                                                 const bf16_t* __restrict__ B, int ldb,
                                                 float* __restrict__ C, int ldc,
                                                 int kb0, int kb1,
                                                 char* __restrict__ smem,
                                                 const float* __restrict__ inv) {
    constexpr int BK = 64;
    bf16_t* As = (bf16_t*)smem;
    bf16_t* Bs = (bf16_t*)(smem + 16384);
    const int tid = threadIdx.x;
    const int lane = tid & 63, wave = tid >> 6;
    const int wm = wave >> 1, wn = wave & 1;
    const int q = lane >> 4, l16 = lane & 15;

    f32x4 acc[4][4] = {};

    const bf16_t* aSrc[4];
    const bf16_t* bSrc[4];
    int ldsOff[4];
#pragma unroll
    for (int it = 0; it < 4; ++it) {
        int c = it * 256 + tid;
        int r = c >> 3, b = c & 7;
        int sb = b ^ (r & 7);
        aSrc[it] = A + (size_t)r * lda + sb * 8;
        bSrc[it] = B + (size_t)r * ldb + sb * 8;
        ldsOff[it] = c * 8;
    }

    for (int kb = kb0; kb < kb1; ++kb) {
        const int k0 = kb * BK;
#pragma unroll
        for (int it = 0; it < 4; ++it) async_copy16(aSrc[it] + k0, &As[ldsOff[it]]);
#pragma unroll
        for (int it = 0; it < 4; ++it) async_copy16(bSrc[it] + k0, &Bs[ldsOff[it]]);
        __syncthreads();
        __builtin_amdgcn_s_setprio(1);
#pragma unroll
        for (int k2 = 0; k2 < 2; ++k2) {
            bf16x8 af[4], bfr[4];
#pragma unroll
            for (int mt = 0; mt < 4; ++mt) {
                int m = wm * 64 + mt * 16 + l16;
                int blk = (k2 * 4 + q) ^ (m & 7);
                af[mt] = *(const bf16x8*)&As[m * BK + blk * 8];
            }
#pragma unroll
            for (int nt = 0; nt < 4; ++nt) {
                int nn = wn * 64 + nt * 16 + l16;
                int blk = (k2 * 4 + q) ^ (nn & 7);
                bfr[nt] = *(const bf16x8*)&Bs[nn * BK + blk * 8];
            }
#pragma unroll
            for (int mt = 0; mt < 4; ++mt)
#pragma unroll
                for (int nt = 0; nt < 4; ++nt)
                    acc[mt][nt] = __builtin_amdgcn_mfma_f32_16x16x32_bf16(
                        af[mt], bfr[nt], acc[mt][nt], 0, 0, 0);
        }
        __builtin_amdgcn_s_setprio(0);
        __syncthreads();
    }

    // Epilogue: two 64-row halves; wave wm owns half wm (row0 = wm*64).
    const int row0 = wm * 64, col0 = wn * 64;
#pragma unroll
    for (int hh = 0; hh < 2; ++hh) {
        if (wm == hh) {
#pragma unroll
            for (int mt = 0; mt < 4; ++mt)
#pragma unroll
                for (int nt = 0; nt < 4; ++nt)
#pragma unroll
                    for (int r = 0; r < 4; ++r) {
                        int lr = row0 + mt * 16 + q * 4 + r;  // global row
                        int rl = lr & 63;                     // row in half
                        int lc = col0 + nt * 16 + l16;
                        float v = acc[mt][nt][r];
                        if (EPI == 2) v *= inv[lr];
                        int cb = lc >> 2;               // 16B chunk (0..31)
                        int sw = cb ^ ((rl >> 2) & 7);
                        *(float*)(smem + rl * 512 + (sw << 4) + ((lc * 4) & 15)) = v;
                    }
        }
        __syncthreads();
        // stream half out: 8 passes x 16B/thread, coalesced 512B rows
#pragma unroll
        for (int p = 0; p < 8; ++p) {
            int g = p * 4096 + tid * 16;
            int r = g >> 9, wb = g & 511;
            int sc = (wb >> 4) ^ ((r >> 2) & 7);
            f32x4 val = *(const f32x4*)(smem + r * 512 + (sc << 4));
            *(f32x4*)&C[(size_t)(hh * 64 + r) * ldc + (wb >> 2)] = val;
        }
        if (hh == 0) __syncthreads();  // before half-1 overwrites the bounce
    }
}

// ---------------- fp8 scores tile, single-buffer 32KB ---------------------
// As [0,16K), Bs [16K,32K); LDS row = 128B = 8 chunks, chunk cb of row r at
// slot cb^(r&7). m97-style loop (8 iters). Epilogue: P = bf16(exp(v*alpha))
// masked, 32KB bounce + sred at smem+32768, 16B coalesced stores; per-row
// partial sums into `partial` (stride 32 floats).
__device__ __forceinline__ void scores_tile_fp8_sb(const u8* __restrict__ A, int lda,
                                                   const u8* __restrict__ B, int ldb,
                                                   bf16_t* __restrict__ C, int ldc,
                                                   float alpha, char* __restrict__ smem,
                                                   float* __restrict__ partial,
                                                   int gr0, int gc0) {
    u8* As = (u8*)smem;
    u8* Bs = (u8*)(smem + 16384);
    const int tid = threadIdx.x;
    const int lane = tid & 63, wave = tid >> 6;
    const int wm = wave >> 1, wn = wave & 1;
    const int q = lane >> 4, l16 = lane & 15;

    f32x4 acc[4][4] = {};

    const u8* aSrc[4];
    const u8* bSrc[4];
    int ldsOff[4];
#pragma unroll
    for (int it = 0; it < 4; ++it) {
        int c = it * 256 + tid;
        int r = c >> 3, b = c & 7;
        int sb = b ^ (r & 7);
        aSrc[it] = A + (size_t)r * lda + sb * 16;
        bSrc[it] = B + (size_t)r * ldb + sb * 16;
        ldsOff[it] = c * 16;
    }

    for (int kb = 0; kb < 8; ++kb) {
        const int k0 = kb * 128;
#pragma unroll
        for (int it = 0; it < 4; ++it) async_copy16(aSrc[it] + k0, &As[ldsOff[it]]);
#pragma unroll
        for (int it = 0; it < 4; ++it) async_copy16(bSrc[it] + k0, &Bs[ldsOff[it]]);
        __syncthreads();
        __builtin_amdgcn_s_setprio(1);
#pragma unroll
        for (int k2 = 0; k2 < 4; ++k2) {
            i64_t af[4], bfr[4];
            const int cb = 2 * k2 + (q >> 1), co = (q & 1) * 8;
#pragma unroll
            for (int mt = 0; mt < 4; ++mt) {
                int m = wm * 64 + mt * 16 + l16;
                af[mt] = *(const i64_t*)&As[m * 128 + ((cb ^ (m & 7)) << 4) + co];
            }
#pragma unroll
            for (int nt = 0; nt < 4; ++nt) {
                int nn = wn * 64 + nt * 16 + l16;
                bfr[nt] = *(const i64_t*)&Bs[nn * 128 + ((cb ^ (nn & 7)) << 4) + co];
            }
#pragma unroll
            for (int mt = 0; mt < 4; ++mt)
#pragma unroll
                for (int nt = 0; nt < 4; ++nt)
                    acc[mt][nt] = __builtin_amdgcn_mfma_f32_16x16x32_fp8_fp8(
                        af[mt], bfr[nt], acc[mt][nt], 0, 0, 0);
        }
        __builtin_amdgcn_s_setprio(0);
        __syncthreads();
    }

    // Epilogue: P = exp(v*alpha) masked -> LDS bounce (bf16, 32KB) + per-row
    // sums via 16-lane shfl into sred (smem+32K, disjoint from bounce).
    float* sred = (float*)(smem + 32768);
    const int row0 = wm * 64, col0 = wn * 64;
    float esum[4][4];
#pragma unroll
    for (int mt = 0; mt < 4; ++mt)
#pragma unroll
        for (int r = 0; r < 4; ++r) esum[mt][r] = 0.f;
#pragma unroll
    for (int mt = 0; mt < 4; ++mt)
#pragma unroll
        for (int nt = 0; nt < 4; ++nt)
#pragma unroll
            for (int r = 0; r < 4; ++r) {
                int lr = row0 + mt * 16 + q * 4 + r;
                int lc = col0 + nt * 16 + l16;
                float pe = (gc0 + lc > gr0 + lr) ? 0.f : __expf(acc[mt][nt][r] * alpha);
                esum[mt][r] += pe;
                int sw = (lc >> 3) ^ ((lr >> 2) & 7);
                *(bf16_t*)(smem + lr * 256 + (sw << 4) + ((lc * 2) & 15)) = (bf16_t)pe;
            }
#pragma unroll
    for (int mt = 0; mt < 4; ++mt)
#pragma unroll
        for (int r = 0; r < 4; ++r) {
#pragma unroll
            for (int off = 1; off < 16; off <<= 1)
                esum[mt][r] += __shfl_xor(esum[mt][r], off, 64);
            if (l16 == 0) sred[(row0 + mt * 16 + q * 4 + r) * 2 + wn] = esum[mt][r];
        }
    __syncthreads();
    // stream P tile out: 8 passes x 16B/thread, coalesced 256B rows
#pragma unroll
    for (int p = 0; p < 8; ++p) {
        int g = p * 4096 + tid * 16;
        int r = g >> 8;
        int wb = g & 255;
        int sc = (wb >> 4) ^ ((r >> 2) & 7);
        f32x4 val = *(const f32x4*)(smem + r * 256 + (sc << 4));
        *(f32x4*)((char*)C + (size_t)r * ((size_t)ldc * 2) + wb) = val;
    }
    if (tid < 128) partial[(size_t)tid * 32] = sred[tid * 2] + sred[tid * 2 + 1];
}

// QK projection only: 512 uniform blocks (2/CU, exactly 1 generation).
// QK = x @ [Wq;Wk]^T -> [4096,2048] fp8.
__global__ __launch_bounds__(256) void k_qkv(const bf16_t* __restrict__ xb,
                                             const bf16_t* __restrict__ wqk,
                                             u8* __restrict__ qk) {
    __shared__ __attribute__((aligned(16))) char smem[65536];
    int b = blockIdx.x;
    int bm = b & 31, bn = b >> 5;  // bn 0..15
    gemm_tile_bf16<0, u8>(xb + (size_t)bm * 128 * 1024, 1024,
                          wqk + (size_t)bn * 128 * 1024, 1024,
                          qk + (size_t)bm * 128 * 2048 + bn * 128, 2048,
                          0, 16, 1.f, smem, nullptr);
}

// Merged dispatch, 784 blocks @ 33KB LDS + launch_bounds(256,4) = 4/CU ->
// SINGLE generation in 1024 slots:
//   b in [0,256):   Vt = Wv @ x^T [1024,4096] bf16 (16 sb iters)
//   b in [256,784): P~ = exp((Q@K^T)/32) causal 128x128 tiles, fp8 sb, 8
//     iters; compact tri grid t = bm(bm+1)/2 + bn (528 tiles); per-row
//     partial sums; diagonal tiles (bn==bm) zero dead slots [bm+1,32).
__global__ __launch_bounds__(256, 4) void k_sv(const bf16_t* __restrict__ xb,
                                               const bf16_t* __restrict__ wvb,
                                               const u8* __restrict__ qk,
                                               bf16_t* __restrict__ vt,
                                               bf16_t* __restrict__ P,
                                               float* __restrict__ rowsum_part) {
    __shared__ __attribute__((aligned(16))) char smem[33792];
    int b = blockIdx.x;
    if (b < 256) {
        int bm = b & 7, bn = b >> 3;  // bn 0..31
        gemm_tile_bf16_sb(wvb + (size_t)bm * 128 * 1024, 1024,
                          xb + (size_t)bn * 128 * 1024, 1024,
                          vt + (size_t)bm * 128 * 4096 + bn * 128, 4096,
                          16, smem);
        return;
    }
    int t = b - 256;  // 0..527
    int bm = (int)((sqrtf(8.f * (float)t + 1.f) - 1.f) * 0.5f);
    while (bm * (bm + 1) / 2 > t) --bm;
    while ((bm + 1) * (bm + 2) / 2 <= t) ++bm;
    int bn = t - bm * (bm + 1) / 2;  // 0..bm
    scores_tile_fp8_sb(qk + (size_t)bm * 128 * 2048, 2048,
                       qk + 1024 + (size_t)bn * 128 * 2048, 2048,
                       P + (size_t)bm * 128 * 4096 + bn * 128, 4096,
                       0.03125f, smem,
                       rowsum_part + (size_t)bm * 128 * 32 + bn,
                       bm * 128, bn * 128);
    if (bn == bm) {  // zero dead rowsum slots for this row block
        float* rp = rowsum_part + (size_t)bm * 128 * 32;
        int tid = threadIdx.x;
        for (int r = tid >> 4; r < 128; r += 16)
            for (int u = bm + 1 + (tid & 15); u < 32; u += 16)
                rp[r * 32 + u] = 0.f;
    }
}

// O = (P~ @ V) * diag(1/rowsum), bf16, BK=64: nk = 2(bm+1) iters.
// Split-K chunk 16 (r12 grid): 80 (bm,s) groups x 8 bn = 640 blocks, all
// resident at 4/CU (1024 slots). Single-split (bm<=7) computes 1/rowsum
// into LDS (smem+32768) and stores direct; multi-split writes fp32 partials
// (16B coalesced via half-bounce) for k_reduce.
__global__ __launch_bounds__(256, 4) void k_pv(const bf16_t* __restrict__ P,
                                               const bf16_t* __restrict__ vt,
                                               const float* __restrict__ rowsum_part,
                                               float* __restrict__ out,
                                               float* __restrict__ partials) {
    __shared__ __attribute__((aligned(16))) char smem[33792];
    float* sInv = (float*)(smem + 32768);  // 512B, disjoint from 32KB bounce
    int b = blockIdx.x;
    int bn = b & 7, g = b >> 3;  // g 0..79
    int bm, s, ns;
    if (g < 8)       { bm = g;                 s = 0;            ns = 1; }
    else if (g < 24) { bm = 8 + (g - 8) / 2;   s = (g - 8) % 2;  ns = 2; }
    else if (g < 48) { bm = 16 + (g - 24) / 3; s = (g - 24) % 3; ns = 3; }
    else             { bm = 24 + (g - 48) / 4; s = (g - 48) % 4; ns = 4; }
    int nk = 2 * (bm + 1);
    int kb0 = s * nk / ns;
    int kb1 = (s + 1) * nk / ns;

    const bf16_t* A = P + (size_t)bm * 128 * 4096;
    const bf16_t* B = vt + (size_t)bn * 128 * 4096;
    if (ns == 1) {
        int tid = threadIdx.x;
        if (tid < 128)
            sInv[tid] = 1.f / sum32(rowsum_part + (size_t)(bm * 128 + tid) * 32);
        // visibility of sInv covered by the K-loop's first __syncthreads
        gemm_tile_f32_sb<2>(A, 4096, B, 4096,
                            out + (size_t)bm * 128 * 1024 + bn * 128, 1024,
                            kb0, kb1, smem, sInv);
    } else {
        int cum = (bm < 16) ? (bm - 8) * 2
                : (bm < 24) ? 16 + (bm - 16) * 3
                            : 40 + (bm - 24) * 4;
        gemm_tile_f32_sb<0>(A, 4096, B, 4096,
                            partials + ((size_t)(cum + s) * 8 + bn) * 16384, 128,
                            kb0, kb1, smem, nullptr);
    }
}

// out tiles for bm in [8,31]: sum 2..4 fp32 partials, scale by 1/rowsum.
// Compact 3072 blocks: t = b%192 -> (bm-8, bn); p = b/192 -> tile 16th
// (8 rows x 128 cols per block); float4/thread.
__global__ __launch_bounds__(256) void k_reduce(const float* __restrict__ partials,
                                                const float* __restrict__ rowsum_part,
                                                float* __restrict__ out) {
    int b = blockIdx.x;
    int t = b % 192, p = b / 192;
    int bm = t % 24 + 8, bn = t / 24;
    int ns = (bm < 16) ? 2 : (bm < 24) ? 3 : 4;
    int cum = (bm < 16) ? (bm - 8) * 2
            : (bm < 24) ? 16 + (bm - 16) * 3
                        : 40 + (bm - 24) * 4;
    __shared__ float sInv[8];
    int tid = threadIdx.x;
    if (tid < 8) {
        int row = bm * 128 + p * 8 + tid;
        sInv[tid] = 1.f / sum32(rowsum_part + (size_t)row * 32);
    }
    __syncthreads();

    int idx = p * 1024 + tid * 4;
    int lr = idx >> 7, lc = idx & 127;
    float sx = 0.f, sy = 0.f, sz = 0.f, sw = 0.f;
    for (int u = 0; u < ns; ++u) {
        const float4 v = *(const float4*)(partials + ((size_t)(cum + u) * 8 + bn) * 16384 + idx);
        sx += v.x; sy += v.y; sz += v.z; sw += v.w;
    }
    float inv = sInv[lr - p * 8];
    float4 o = {sx * inv, sy * inv, sz * inv, sw * inv};
    *(float4*)(out + (size_t)(bm * 128 + lr) * 1024 + bn * 128 + lc) = o;
}

// fp32 -> bf16 casts: x -> x_bf, Wq|Wk -> Wqk (concat), Wv -> Wv_bf.
__global__ __launch_bounds__(256) void cast_to_bf16(const float* __restrict__ x,
                                                    const float* __restrict__ Wq,
                                                    const float* __restrict__ Wk,
                                                    const float* __restrict__ Wv,
                                                    bf16_t* __restrict__ xb,
                                                    bf16_t* __restrict__ wqk,
                                                    bf16_t* __restrict__ wv) {
    const int NX = (4096 * 1024) / 4;
    const int NW = (1024 * 1024) / 4;
    int idx = blockIdx.x * 256 + threadIdx.x;
    const float* src;
    bf16_t* dst;
    int off;
    if (idx < NX) {
        src = x; dst = xb; off = idx;
    } else if (idx < NX + NW) {
        src = Wq; dst = wqk; off = idx - NX;
    } else if (idx < NX + 2 * NW) {
        src = Wk; dst = wqk + (size_t)NW * 4; off = idx - NX - NW;
    } else {
        src = Wv; dst = wv; off = idx - NX - 2 * NW;
    }
    float4 f = ((const float4*)src)[off];
    bf16x4v o;
    o.x = (bf16_t)f.x; o.y = (bf16_t)f.y; o.z = (bf16_t)f.z; o.w = (bf16_t)f.w;
    *(bf16x4v*)(dst + (size_t)off * 4) = o;
}

extern "C" void kernel_launch(void* const* d_in, const int* in_sizes, int n_in,
                              void* d_out, int out_size, void* d_ws, size_t ws_size,
                              hipStream_t stream) {
    (void)in_sizes; (void)n_in; (void)out_size; (void)ws_size;
    const float* x  = (const float*)d_in[0];
    const float* Wq = (const float*)d_in[1];
    const float* Wk = (const float*)d_in[2];
    const float* Wv = (const float*)d_in[3];
    float* out = (float*)d_out;

    char* ws = (char*)d_ws;
    bf16_t* xb   = (bf16_t*)(ws + (size_t)0);
    bf16_t* wqk  = (bf16_t*)(ws + ((size_t)8 << 20));
    bf16_t* wvb  = (bf16_t*)(ws + ((size_t)12 << 20));
    u8*     qk   = (u8*)(ws + ((size_t)14 << 20));
    bf16_t* vt   = (bf16_t*)(ws + ((size_t)22 << 20));
    bf16_t* P    = (bf16_t*)(ws + ((size_t)30 << 20));
    float* rowsp = (float*)(ws + ((size_t)62 << 20));
    float* parts = (float*)(ws + ((size_t)64 << 20));

    cast_to_bf16<<<7168, 256, 0, stream>>>(x, Wq, Wk, Wv, xb, wqk, wvb);

    // QK (fp8) = x@[Wq;Wk]^T (512 blocks, 2/CU, 1 generation)
    k_qkv<<<512, 256, 0, stream>>>(xb, wqk, qk);

    // Vt (bf16) = Wv@x^T + P~ = exp((Q@K^T)/32) causal (784 blocks, 4/CU)
    k_sv<<<784, 256, 0, stream>>>(xb, wvb, qk, vt, P, rowsp);

    // out = (P~ @ V) * diag(1/rowsum): split-K chunk 16 (640 blocks, 4/CU)
    k_pv<<<640, 256, 0, stream>>>(P, vt, rowsp, out, parts);
    k_reduce<<<3072, 256, 0, stream>>>(parts, rowsp, out);
}

// Round 10
// 165.398 us; speedup vs baseline: 1.0091x; 1.0091x over previous
//
#include <hip/hip_runtime.h>
#include <hip/hip_bf16.h>

// Causal attention, S=4096, d=1024, fp32 in/out.
// bf16 MFMA for projections and PV; fp8 e4m3 MFMA (BK=128B) for scores only.
//
// Round-20 (this round):
//  - k_pv/k_reduce REVERT to r16 dbuf/504-block config (r19 proved sb@4/CU
//    is neutral for k_pv: no packing unlock -> no gain; lesson recorded).
//  - k_sv tail fix: Vt blocks are 2u (16 iters), scores 1u (8 iters);
//    1040u/256CU = 4.06u ideal but 784 blocks put a 3rd score tile on 16
//    CUs -> makespan 5u (+23%). Split the 16 tiles (bm=31,bn>=16) into 32
//    half-row blocks (~0.6u) appended at the tail -> makespan ~4.6u.
//    Per-element accumulation order unchanged -> absmax canary 0.02734375.
//
// Round-17: k_sv sb 33KB @4/CU (-9us). Round-16: k_pv 1-gen regrid (-12us).
// Pipeline levers closed (r2/r3/r5).
//
// Workspace (256 MiB):
//   [0,8M)    x_bf  [4096,1024] bf16
//   [8M,12M)  Wqk   [2048,1024] bf16 (Wq rows 0..1023, Wk rows 1024..2047)
//   [12M,14M) Wv_bf [1024,1024] bf16
//   [14M,22M) QK    [4096,2048] fp8  (Q cols 0..1023, K cols 1024..2047)
//   [22M,30M) Vt    [1024,4096] bf16 (V^T, computed directly as Wv @ x^T)
//   [30M,62M) P~    [4096,4096] bf16 (exp(s/32), masked, unnormalized)
//   [62M,62.5M) rowsum_part [4096][32] fp32 (slot bn; dead slots zeroed)
//   [64M,92M) PV fp32 partials (52 multi-split groups x 8 bn x 64 KB)

typedef __bf16 bf16_t;
typedef __bf16 bf16x4v __attribute__((ext_vector_type(4)));
typedef __bf16 bf16x8 __attribute__((ext_vector_type(8)));
typedef float f32x4 __attribute__((ext_vector_type(4)));
typedef unsigned char u8;
typedef long long i64_t;

#define AS1 __attribute__((address_space(1)))
#define AS3 __attribute__((address_space(3)))
#define WAIT_VMCNT(N) asm volatile("s_waitcnt vmcnt(" #N ")" ::: "memory")
#define BARRIER_RAW() asm volatile("s_barrier" ::: "memory")

__device__ __forceinline__ void async_copy16(const void* g, void* l) {
    // 16B/lane direct global->LDS; LDS dest = wave-uniform base + lane*16
    __builtin_amdgcn_global_load_lds((AS1 void*)(g), (AS3 void*)(l), 16, 0, 0);
}

__device__ __forceinline__ u8 f32_to_fp8(float v) {
    // OCP e4m3 on gfx950 (HW conversion); layout validated in round 6
    return (u8)(__builtin_amdgcn_cvt_pk_fp8_f32(v, v, 0, false) & 0xff);
}

__device__ __forceinline__ void store_conv(float* p, float v) { *p = v; }
__device__ __forceinline__ void store_conv(bf16_t* p, float v) { *p = (bf16_t)v; }
__device__ __forceinline__ void store_conv(u8* p, float v) { *p = f32_to_fp8(v); }

// Sum of 32 consecutive floats (8x float4), for 1/rowsum computation.
__device__ __forceinline__ float sum32(const float* p) {
    const f32x4* v = (const f32x4*)p;
    float s = 0.f;
#pragma unroll
    for (int u = 0; u < 8; ++u) {
        f32x4 a = v[u];
        s += a[0] + a[1] + a[2] + a[3];
    }
    return s;
}

// ---------------- bf16 tile: BM=128, BN=128, BK=64 (r12, dbuf 64KB) -------
// Double-buffered staging: A bufs [0,16K),[16K,32K); B bufs [32K,48K),[48K,64K).
// XOR-swizzled LDS (16B chunk b of row r holds k-chunk b^(r&7)).
// Counted-vmcnt 2-barrier K-loop. Epilogue: LDS-bounce -> 16B coalesced stores.
// EPI 0: C = v*alpha | EPI 2: C = v * inv[row] (inv indexed by tile-local row)
template <int EPI, typename OutT>
__device__ __forceinline__ void gemm_tile_bf16(const bf16_t* __restrict__ A, int lda,
                                               const bf16_t* __restrict__ B, int ldb,
                                               OutT* __restrict__ C, int ldc,
                                               int kb0, int kb1, float alpha,
                                               char* __restrict__ smem,
                                               const float* __restrict__ inv) {
    constexpr int BK = 64;
    bf16_t* As = (bf16_t*)smem;            // 2 x 8192 elems (16KB each)
    bf16_t* Bs = (bf16_t*)(smem + 32768);  // 2 x 8192 elems
    const int tid = threadIdx.x;
    const int lane = tid & 63, wave = tid >> 6;
    const int wm = wave >> 1, wn = wave & 1;
    const int q = lane >> 4, l16 = lane & 15;

    f32x4 acc[4][4] = {};

    const bf16_t* aSrc[4];
    const bf16_t* bSrc[4];
    int ldsOff[4];
#pragma unroll
    for (int it = 0; it < 4; ++it) {
        int c = it * 256 + tid;
        int r = c >> 3, b = c & 7;
        int sb = b ^ (r & 7);
        aSrc[it] = A + (size_t)r * lda + sb * 8;
        bSrc[it] = B + (size_t)r * ldb + sb * 8;
        ldsOff[it] = c * 8;
    }

    // prologue: stage first K-step into buffer 0 (8 loads in flight)
    {
        const int k0 = kb0 * BK;
#pragma unroll
        for (int it = 0; it < 4; ++it) async_copy16(aSrc[it] + k0, &As[ldsOff[it]]);
#pragma unroll
        for (int it = 0; it < 4; ++it) async_copy16(bSrc[it] + k0, &Bs[ldsOff[it]]);
    }

    int cur = 0;
    for (int kb = kb0; kb < kb1; ++kb) {
        if (kb + 1 < kb1) {  // prefetch next K-step into alternate buffer
            const int k0 = (kb + 1) * BK;
            const int boff = (cur ^ 1) * 8192;
#pragma unroll
            for (int it = 0; it < 4; ++it) async_copy16(aSrc[it] + k0, &As[boff + ldsOff[it]]);
#pragma unroll
            for (int it = 0; it < 4; ++it) async_copy16(bSrc[it] + k0, &Bs[boff + ldsOff[it]]);
            WAIT_VMCNT(8);   // tile-kb loads (8 oldest) retired; kb+1 in flight
        } else {
            WAIT_VMCNT(0);   // tail: drain everything
        }
        __builtin_amdgcn_sched_barrier(0);
        BARRIER_RAW();       // all waves' tile-kb loads landed
        const bf16_t* Ab = As + cur * 8192;
        const bf16_t* Bb = Bs + cur * 8192;
        __builtin_amdgcn_s_setprio(1);
#pragma unroll
        for (int k2 = 0; k2 < 2; ++k2) {
            bf16x8 af[4], bfr[4];
#pragma unroll
            for (int mt = 0; mt < 4; ++mt) {
                int m = wm * 64 + mt * 16 + l16;
                int blk = (k2 * 4 + q) ^ (m & 7);
                af[mt] = *(const bf16x8*)&Ab[m * BK + blk * 8];
            }
#pragma unroll
            for (int nt = 0; nt < 4; ++nt) {
                int nn = wn * 64 + nt * 16 + l16;
                int blk = (k2 * 4 + q) ^ (nn & 7);
                bfr[nt] = *(const bf16x8*)&Bb[nn * BK + blk * 8];
            }
#pragma unroll
            for (int mt = 0; mt < 4; ++mt)
#pragma unroll
                for (int nt = 0; nt < 4; ++nt)
                    acc[mt][nt] = __builtin_amdgcn_mfma_f32_16x16x32_bf16(
                        af[mt], bfr[nt], acc[mt][nt], 0, 0, 0);
        }
        __builtin_amdgcn_s_setprio(0);
        BARRIER_RAW();       // reads of buf done -> next iter may overwrite
        cur ^= 1;
    }

    // Epilogue: bounce C tile (128x128 OutT) through dead staging LDS.
    // C/D layout: col = lane&15, row = (lane>>4)*4 + reg.
    constexpr int S = (int)sizeof(OutT);
    constexpr int RB = 128 * S;  // bytes per tile row
    const int row0 = wm * 64, col0 = wn * 64;
#pragma unroll
    for (int mt = 0; mt < 4; ++mt)
#pragma unroll
        for (int nt = 0; nt < 4; ++nt)
#pragma unroll
            for (int r = 0; r < 4; ++r) {
                int lr = row0 + mt * 16 + q * 4 + r;
                int lc = col0 + nt * 16 + l16;
                float v = acc[mt][nt][r];
                v = (EPI == 2) ? v * inv[lr] : v * alpha;
                int cb = (lc * S) >> 4;
                int sw = cb ^ ((lr >> 2) & 7);
                store_conv((OutT*)(smem + lr * RB + (sw << 4) + ((lc * S) & 15)), v);
            }
    __syncthreads();
    // stream out: 16B/thread/pass, fully coalesced (4 threads = one 64B line)
#pragma unroll
    for (int p = 0; p < 4 * S; ++p) {
        int g = p * 4096 + tid * 16;  // linear byte index in tile
        int r = g / RB;
        int wb = g & (RB - 1);
        int sc = (wb >> 4) ^ ((r >> 2) & 7);
        f32x4 val = *(const f32x4*)(smem + r * RB + (sc << 4));
        *(f32x4*)((char*)C + (size_t)r * ((size_t)ldc * S) + wb) = val;
    }
}

// ---------------- bf16 tile, single-buffer 32KB (m97 structure) -----------
// As [0,16K), Bs [16K,32K). Per iter: stage 8 loads -> __syncthreads ->
// ds_read + 32 MFMA -> __syncthreads. 4 blocks/CU; cross-block wave overlap
// hides the drain (m97/m114). Epilogue: 32KB LDS bounce (bf16 out).
__device__ __forceinline__ void gemm_tile_bf16_sb(const bf16_t* __restrict__ A, int lda,
                                                  const bf16_t* __restrict__ B, int ldb,
                                                  bf16_t* __restrict__ C, int ldc,
                                                  int kb1, char* __restrict__ smem) {
    constexpr int BK = 64;
    bf16_t* As = (bf16_t*)smem;            // 8192 elems (16KB)
    bf16_t* Bs = (bf16_t*)(smem + 16384);  // 8192 elems
    const int tid = threadIdx.x;
    const int lane = tid & 63, wave = tid >> 6;
    const int wm = wave >> 1, wn = wave & 1;
    const int q = lane >> 4, l16 = lane & 15;

    f32x4 acc[4][4] = {};

    const bf16_t* aSrc[4];
    const bf16_t* bSrc[4];
    int ldsOff[4];
#pragma unroll
    for (int it = 0; it < 4; ++it) {
        int c = it * 256 + tid;
        int r = c >> 3, b = c & 7;
        int sb = b ^ (r & 7);
        aSrc[it] = A + (size_t)r * lda + sb * 8;
        bSrc[it] = B + (size_t)r * ldb + sb * 8;
        ldsOff[it] = c * 8;
    }

    for (int kb = 0; kb < kb1; ++kb) {
        const int k0 = kb * BK;
#pragma unroll
        for (int it = 0; it < 4; ++it) async_copy16(aSrc[it] + k0, &As[ldsOff[it]]);
#pragma unroll
        for (int it = 0; it < 4; ++it) async_copy16(bSrc[it] + k0, &Bs[ldsOff[it]]);
        __syncthreads();
        __builtin_amdgcn_s_setprio(1);
#pragma unroll
        for (int k2 = 0; k2 < 2; ++k2) {
            bf16x8 af[4], bfr[4];
#pragma unroll
            for (int mt = 0; mt < 4; ++mt) {
                int m = wm * 64 + mt * 16 + l16;
                int blk = (k2 * 4 + q) ^ (m & 7);
                af[mt] = *(const bf16x8*)&As[m * BK + blk * 8];
            }
#pragma unroll
            for (int nt = 0; nt < 4; ++nt) {
                int nn = wn * 64 + nt * 16 + l16;
                int blk = (k2 * 4 + q) ^ (nn & 7);
                bfr[nt] = *(const bf16x8*)&Bs[nn * BK + blk * 8];
            }
#pragma unroll
            for (int mt = 0; mt < 4; ++mt)
#pragma unroll
                for (int nt = 0; nt < 4; ++nt)
                    acc[mt][nt] = __builtin_amdgcn_mfma_f32_16x16x32_bf16(
                        af[mt], bfr[nt], acc[mt][nt], 0, 0, 0);
        }
        __builtin_amdgcn_s_setprio(0);
        __syncthreads();  // reads done -> next stage may overwrite
    }

    // Epilogue: bounce C tile (128x128 bf16, 32KB) through staging LDS.
    constexpr int RB = 256;
    const int row0 = wm * 64, col0 = wn * 64;
#pragma unroll
    for (int mt = 0; mt < 4; ++mt)
#pragma unroll
        for (int nt = 0; nt < 4; ++nt)
#pragma unroll
            for (int r = 0; r < 4; ++r) {
                int lr = row0 + mt * 16 + q * 4 + r;
                int lc = col0 + nt * 16 + l16;
                int cb = (lc * 2) >> 4;
                int sw = cb ^ ((lr >> 2) & 7);
                *(bf16_t*)(smem + lr * RB + (sw << 4) + ((lc * 2) & 15)) =
                    (bf16_t)acc[mt][nt][r];
            }
    __syncthreads();
#pragma unroll
    for (int p = 0; p < 8; ++p) {
        int g = p * 4096 + tid * 16;
        int r = g >> 8, wb = g & 255;
        int sc = (wb >> 4) ^ ((r >> 2) & 7);
        f32x4 val = *(const f32x4*)(smem + r * RB + (sc << 4));
        *(f32x4*)((char*)C + (size_t)r * ((size_t)ldc * 2) + wb) = val;
    }
}

// ---------------- fp8 scores tile, single-buffer 32KB (full 128 rows) -----
// As [0,16K), Bs [16K,32K); LDS row = 128B = 8 chunks, chunk cb of row r at
// slot cb^(r&7). m97-style loop (8 iters). Epilogue: P = bf16(exp(v*alpha))
// masked, 32KB bounce + sred at smem+32768, 16B coalesced stores; per-row
// partial sums into `partial` (stride 32 floats).
__device__ __forceinline__ void scores_tile_fp8_sb(const u8* __restrict__ A, int lda,
                                                   const u8* __restrict__ B, int ldb,
                                                   bf16_t* __restrict__ C, int ldc,
                                                   float alpha, char* __restrict__ smem,
                                                   float* __restrict__ partial,
                                                   int gr0, int gc0) {
    u8* As = (u8*)smem;
    u8* Bs = (u8*)(smem + 16384);
    const int tid = threadIdx.x;
    const int lane = tid & 63, wave = tid >> 6;
    const int wm = wave >> 1, wn = wave & 1;
    const int q = lane >> 4, l16 = lane & 15;

    f32x4 acc[4][4] = {};

    const u8* aSrc[4];
    const u8* bSrc[4];
    int ldsOff[4];
#pragma unroll
    for (int it = 0; it < 4; ++it) {
        int c = it * 256 + tid;
        int r = c >> 3, b = c & 7;
        int sb = b ^ (r & 7);
        aSrc[it] = A + (size_t)r * lda + sb * 16;
        bSrc[it] = B + (size_t)r * ldb + sb * 16;
        ldsOff[it] = c * 16;
    }

    for (int kb = 0; kb < 8; ++kb) {
        const int k0 = kb * 128;
#pragma unroll
        for (int it = 0; it < 4; ++it) async_copy16(aSrc[it] + k0, &As[ldsOff[it]]);
#pragma unroll
        for (int it = 0; it < 4; ++it) async_copy16(bSrc[it] + k0, &Bs[ldsOff[it]]);
        __syncthreads();
        __builtin_amdgcn_s_setprio(1);
#pragma unroll
        for (int k2 = 0; k2 < 4; ++k2) {
            i64_t af[4], bfr[4];
            const int cb = 2 * k2 + (q >> 1), co = (q & 1) * 8;
#pragma unroll
            for (int mt = 0; mt < 4; ++mt) {
                int m = wm * 64 + mt * 16 + l16;
                af[mt] = *(const i64_t*)&As[m * 128 + ((cb ^ (m & 7)) << 4) + co];
            }
#pragma unroll
            for (int nt = 0; nt < 4; ++nt) {
                int nn = wn * 64 + nt * 16 + l16;
                bfr[nt] = *(const i64_t*)&Bs[nn * 128 + ((cb ^ (nn & 7)) << 4) + co];
            }
#pragma unroll
            for (int mt = 0; mt < 4; ++mt)
#pragma unroll
                for (int nt = 0; nt < 4; ++nt)
                    acc[mt][nt] = __builtin_amdgcn_mfma_f32_16x16x32_fp8_fp8(
                        af[mt], bfr[nt], acc[mt][nt], 0, 0, 0);
        }
        __builtin_amdgcn_s_setprio(0);
        __syncthreads();
    }

    // Epilogue: P = exp(v*alpha) masked -> LDS bounce (bf16, 32KB) + per-row
    // sums via 16-lane shfl into sred (smem+32K, disjoint from bounce).
    float* sred = (float*)(smem + 32768);
    const int row0 = wm * 64, col0 = wn * 64;
    float esum[4][4];
#pragma unroll
    for (int mt = 0; mt < 4; ++mt)
#pragma unroll
        for (int r = 0; r < 4; ++r) esum[mt][r] = 0.f;
#pragma unroll
    for (int mt = 0; mt < 4; ++mt)
#pragma unroll
        for (int nt = 0; nt < 4; ++nt)
#pragma unroll
            for (int r = 0; r < 4; ++r) {
                int lr = row0 + mt * 16 + q * 4 + r;
                int lc = col0 + nt * 16 + l16;
                float pe = (gc0 + lc > gr0 + lr) ? 0.f : __expf(acc[mt][nt][r] * alpha);
                esum[mt][r] += pe;
                int sw = (lc >> 3) ^ ((lr >> 2) & 7);
                *(bf16_t*)(smem + lr * 256 + (sw << 4) + ((lc * 2) & 15)) = (bf16_t)pe;
            }
#pragma unroll
    for (int mt = 0; mt < 4; ++mt)
#pragma unroll
        for (int r = 0; r < 4; ++r) {
#pragma unroll
            for (int off = 1; off < 16; off <<= 1)
                esum[mt][r] += __shfl_xor(esum[mt][r], off, 64);
            if (l16 == 0) sred[(row0 + mt * 16 + q * 4 + r) * 2 + wn] = esum[mt][r];
        }
    __syncthreads();
    // stream P tile out: 8 passes x 16B/thread, coalesced 256B rows
#pragma unroll
    for (int p = 0; p < 8; ++p) {
        int g = p * 4096 + tid * 16;
        int r = g >> 8;
        int wb = g & 255;
        int sc = (wb >> 4) ^ ((r >> 2) & 7);
        f32x4 val = *(const f32x4*)(smem + r * 256 + (sc << 4));
        *(f32x4*)((char*)C + (size_t)r * ((size_t)ldc * 2) + wb) = val;
    }
    if (tid < 128) partial[(size_t)tid * 32] = sred[tid * 2] + sred[tid * 2 + 1];
}

// ---------------- fp8 scores HALF tile (64 Q-rows), tail filler -----------
// Covers tile rows {32h..32h+31} U {64+32h..95+32h}: wave wm owns sub-block
// wm (mt<2); As rows 0..63 map linearly. Same kb/k2 accumulation order as
// the full tile -> bit-identical P elements. ~0.6x duration of a full tile.
__device__ __forceinline__ void scores_tile_fp8_sb_half(
        const u8* __restrict__ A, int lda, const u8* __restrict__ B, int ldb,
        bf16_t* __restrict__ C, int ldc, float alpha, char* __restrict__ smem,
        float* __restrict__ partial, int gr0, int gc0, int half) {
    u8* As = (u8*)smem;            // 64 rows x 128B = 8KB used
    u8* Bs = (u8*)(smem + 16384);
    const int tid = threadIdx.x;
    const int lane = tid & 63, wave = tid >> 6;
    const int wm = wave >> 1, wn = wave & 1;
    const int q = lane >> 4, l16 = lane & 15;

    f32x4 acc[2][4] = {};

    const u8* aSrc[2];
    const u8* bSrc[4];
    int aOff[2], bOff[4];
#pragma unroll
    for (int it = 0; it < 2; ++it) {
        int c = it * 256 + tid;
        int r = c >> 3, b = c & 7;      // r = LDS row 0..63
        int sb = b ^ (r & 7);
        int srcRow = r + 32 * half + 32 * it;  // global tile row
        aSrc[it] = A + (size_t)srcRow * lda + sb * 16;
        aOff[it] = c * 16;
    }
#pragma unroll
    for (int it = 0; it < 4; ++it) {
        int c = it * 256 + tid;
        int r = c >> 3, b = c & 7;
        int sb = b ^ (r & 7);
        bSrc[it] = B + (size_t)r * ldb + sb * 16;
        bOff[it] = c * 16;
    }

    for (int kb = 0; kb < 8; ++kb) {
        const int k0 = kb * 128;
#pragma unroll
        for (int it = 0; it < 2; ++it) async_copy16(aSrc[it] + k0, &As[aOff[it]]);
#pragma unroll
        for (int it = 0; it < 4; ++it) async_copy16(bSrc[it] + k0, &Bs[bOff[it]]);
        __syncthreads();
        __builtin_amdgcn_s_setprio(1);
#pragma unroll
        for (int k2 = 0; k2 < 4; ++k2) {
            i64_t af[2], bfr[4];
            const int cb = 2 * k2 + (q >> 1), co = (q & 1) * 8;
#pragma unroll
            for (int mt = 0; mt < 2; ++mt) {
                int m = wm * 32 + mt * 16 + l16;  // As row
                af[mt] = *(const i64_t*)&As[m * 128 + ((cb ^ (m & 7)) << 4) + co];
            }
#pragma unroll
            for (int nt = 0; nt < 4; ++nt) {
                int nn = wn * 64 + nt * 16 + l16;
                bfr[nt] = *(const i64_t*)&Bs[nn * 128 + ((cb ^ (nn & 7)) << 4) + co];
            }
#pragma unroll
            for (int mt = 0; mt < 2; ++mt)
#pragma unroll
                for (int nt = 0; nt < 4; ++nt)
                    acc[mt][nt] = __builtin_amdgcn_mfma_f32_16x16x32_fp8_fp8(
                        af[mt], bfr[nt], acc[mt][nt], 0, 0, 0);
        }
        __builtin_amdgcn_s_setprio(0);
        __syncthreads();
    }

    // Epilogue: 64-row bounce (16KB) keyed by compact row cr; tile row =
    // (cr>>5)*64 + 32*half + (cr&31).
    float* sred = (float*)(smem + 32768);
    const int col0 = wn * 64;
    float esum[2][4];
#pragma unroll
    for (int mt = 0; mt < 2; ++mt)
#pragma unroll
        for (int r = 0; r < 4; ++r) esum[mt][r] = 0.f;
#pragma unroll
    for (int mt = 0; mt < 2; ++mt)
#pragma unroll
        for (int nt = 0; nt < 4; ++nt)
#pragma unroll
            for (int r = 0; r < 4; ++r) {
                int cr = wm * 32 + mt * 16 + q * 4 + r;
                int trow = ((cr >> 5) << 6) + 32 * half + (cr & 31);
                int lc = col0 + nt * 16 + l16;
                float pe = (gc0 + lc > gr0 + trow) ? 0.f : __expf(acc[mt][nt][r] * alpha);
                esum[mt][r] += pe;
                int sw = (lc >> 3) ^ ((cr >> 2) & 7);
                *(bf16_t*)(smem + cr * 256 + (sw << 4) + ((lc * 2) & 15)) = (bf16_t)pe;
            }
#pragma unroll
    for (int mt = 0; mt < 2; ++mt)
#pragma unroll
        for (int r = 0; r < 4; ++r) {
#pragma unroll
            for (int off = 1; off < 16; off <<= 1)
                esum[mt][r] += __shfl_xor(esum[mt][r], off, 64);
            if (l16 == 0)
                sred[(wm * 32 + mt * 16 + q * 4 + r) * 2 + wn] = esum[mt][r];
        }
    __syncthreads();
    // stream out: 4 passes x 16B/thread
#pragma unroll
    for (int p = 0; p < 4; ++p) {
        int g = p * 4096 + tid * 16;
        int cr = g >> 8, wb = g & 255;
        int sc = (wb >> 4) ^ ((cr >> 2) & 7);
        f32x4 val = *(const f32x4*)(smem + cr * 256 + (sc << 4));
        int trow = ((cr >> 5) << 6) + 32 * half + (cr & 31);
        *(f32x4*)((char*)C + (size_t)trow * ((size_t)ldc * 2) + wb) = val;
    }
    if (tid < 64) {
        int trow = ((tid >> 5) << 6) + 32 * half + (tid & 31);
        partial[(size_t)trow * 32] = sred[tid * 2] + sred[tid * 2 + 1];
    }
}

// QK projection only: 512 uniform blocks (2/CU, exactly 1 generation).
// QK = x @ [Wq;Wk]^T -> [4096,2048] fp8.
__global__ __launch_bounds__(256) void k_qkv(const bf16_t* __restrict__ xb,
                                             const bf16_t* __restrict__ wqk,
                                             u8* __restrict__ qk) {
    __shared__ __attribute__((aligned(16))) char smem[65536];
    int b = blockIdx.x;
    int bm = b & 31, bn = b >> 5;  // bn 0..15
    gemm_tile_bf16<0, u8>(xb + (size_t)bm * 128 * 1024, 1024,
                          wqk + (size_t)bn * 128 * 1024, 1024,
                          qk + (size_t)bm * 128 * 2048 + bn * 128, 2048,
                          0, 16, 1.f, smem, nullptr);
}

// Merged dispatch, 800 blocks @ 33KB LDS + launch_bounds(256,4) = 4/CU, all
// resident:
//   b in [0,256):   Vt = Wv @ x^T [1024,4096] bf16 (16 sb iters, ~2u)
//   b in [256,768): full scores tiles t = 0..511 (8 sb iters, ~1u)
//   b in [768,800): 32 HALF tiles covering t = 512..527 (bm=31, bn 16..31),
//     ~0.6u tail fillers -> makespan ~4.6u instead of 5u.
__global__ __launch_bounds__(256, 4) void k_sv(const bf16_t* __restrict__ xb,
                                               const bf16_t* __restrict__ wvb,
                                               const u8* __restrict__ qk,
                                               bf16_t* __restrict__ vt,
                                               bf16_t* __restrict__ P,
                                               float* __restrict__ rowsum_part) {
    __shared__ __attribute__((aligned(16))) char smem[33792];
    int b = blockIdx.x;
    if (b < 256) {
        int bm = b & 7, bn = b >> 3;  // bn 0..31
        gemm_tile_bf16_sb(wvb + (size_t)bm * 128 * 1024, 1024,
                          xb + (size_t)bn * 128 * 1024, 1024,
                          vt + (size_t)bm * 128 * 4096 + bn * 128, 4096,
                          16, smem);
        return;
    }
    if (b < 768) {
        int t = b - 256;  // 0..511 (tiles (31,16..31) excluded -> halves)
        int bm = (int)((sqrtf(8.f * (float)t + 1.f) - 1.f) * 0.5f);
        while (bm * (bm + 1) / 2 > t) --bm;
        while ((bm + 1) * (bm + 2) / 2 <= t) ++bm;
        int bn = t - bm * (bm + 1) / 2;  // 0..bm
        scores_tile_fp8_sb(qk + (size_t)bm * 128 * 2048, 2048,
                           qk + 1024 + (size_t)bn * 128 * 2048, 2048,
                           P + (size_t)bm * 128 * 4096 + bn * 128, 4096,
                           0.03125f, smem,
                           rowsum_part + (size_t)bm * 128 * 32 + bn,
                           bm * 128, bn * 128);
        if (bn == bm) {  // zero dead rowsum slots for this row block
            float* rp = rowsum_part + (size_t)bm * 128 * 32;
            int tid = threadIdx.x;
            for (int r = tid >> 4; r < 128; r += 16)
                for (int u = bm + 1 + (tid & 15); u < 32; u += 16)
                    rp[r * 32 + u] = 0.f;
        }
        return;
    }
    // half tiles: bm = 31, bn = 16 + j/2, half = j&1 (no dead slots for bm=31)
    int j = b - 768;  // 0..31
    int bn = 16 + (j >> 1);
    int half = j & 1;
    scores_tile_fp8_sb_half(qk + (size_t)31 * 128 * 2048, 2048,
                            qk + 1024 + (size_t)bn * 128 * 2048, 2048,
                            P + (size_t)31 * 128 * 4096 + bn * 128, 4096,
                            0.03125f, smem,
                            rowsum_part + (size_t)31 * 128 * 32 + bn,
                            31 * 128, bn * 128, half);
}

// O = (P~ @ V) * diag(1/rowsum), bf16, BK=64: nk = 2(bm+1) iters.
// Split-K chunk <=22: ns = 1 (bm 0..10) / 2 (bm 11..21) / 3 (bm 22..31).
// Groups: 11 + 22 + 30 = 63; x 8 bn = 504 blocks = ONE generation at 2/CU.
// (r16 config: r19 proved sb@4/CU is neutral here -> keep dbuf.)
__global__ __launch_bounds__(256) void k_pv(const bf16_t* __restrict__ P,
                                            const bf16_t* __restrict__ vt,
                                            const float* __restrict__ rowsum_part,
                                            float* __restrict__ out,
                                            float* __restrict__ partials) {
    __shared__ __attribute__((aligned(16))) char smem[65536];
    __shared__ float sInv[128];
    int b = blockIdx.x;
    int bn = b & 7, g = b >> 3;  // g 0..62
    int bm, s, ns;
    if (g < 11)      { bm = g;                  s = 0;             ns = 1; }
    else if (g < 33) { bm = 11 + (g - 11) / 2;  s = (g - 11) % 2;  ns = 2; }
    else             { bm = 22 + (g - 33) / 3;  s = (g - 33) % 3;  ns = 3; }
    int nk = 2 * (bm + 1);
    int kb0 = s * nk / ns;
    int kb1 = (s + 1) * nk / ns;

    const bf16_t* A = P + (size_t)bm * 128 * 4096;
    const bf16_t* B = vt + (size_t)bn * 128 * 4096;
    if (ns == 1) {
        int tid = threadIdx.x;
        if (tid < 128)
            sInv[tid] = 1.f / sum32(rowsum_part + (size_t)(bm * 128 + tid) * 32);
        // visibility of sInv covered by the K-loop's first barrier
        gemm_tile_bf16<2, float>(A, 4096, B, 4096,
                                 out + (size_t)bm * 128 * 1024 + bn * 128, 1024,
                                 kb0, kb1, 1.f, smem, sInv);
    } else {
        int cum = (bm < 22) ? (bm - 11) * 2 : 22 + (bm - 22) * 3;
        gemm_tile_bf16<0, float>(A, 4096, B, 4096,
                                 partials + ((size_t)(cum + s) * 8 + bn) * 16384, 128,
                                 kb0, kb1, 1.f, smem, nullptr);
    }
}

// out tiles for bm in [11,31]: sum 2..3 fp32 partials, scale by 1/rowsum.
// 21 bm x 8 bn = 168 tiles; x16 sub-blocks (8 rows x 128 cols, float4/thr)
// = 2688 blocks.
__global__ __launch_bounds__(256) void k_reduce(const float* __restrict__ partials,
                                                const float* __restrict__ rowsum_part,
                                                float* __restrict__ out) {
    int b = blockIdx.x;
    int t = b % 168, p = b / 168;
    int bm = 11 + t % 21, bn = t / 21;
    int ns = (bm < 22) ? 2 : 3;
    int cum = (bm < 22) ? (bm - 11) * 2 : 22 + (bm - 22) * 3;
    __shared__ float sInv[8];
    int tid = threadIdx.x;
    if (tid < 8) {
        int row = bm * 128 + p * 8 + tid;
        sInv[tid] = 1.f / sum32(rowsum_part + (size_t)row * 32);
    }
    __syncthreads();

    int idx = p * 1024 + tid * 4;
    int lr = idx >> 7, lc = idx & 127;
    float sx = 0.f, sy = 0.f, sz = 0.f, sw = 0.f;
    for (int u = 0; u < ns; ++u) {
        const float4 v = *(const float4*)(partials + ((size_t)(cum + u) * 8 + bn) * 16384 + idx);
        sx += v.x; sy += v.y; sz += v.z; sw += v.w;
    }
    float inv = sInv[lr - p * 8];
    float4 o = {sx * inv, sy * inv, sz * inv, sw * inv};
    *(float4*)(out + (size_t)(bm * 128 + lr) * 1024 + bn * 128 + lc) = o;
}

// fp32 -> bf16 casts: x -> x_bf, Wq|Wk -> Wqk (concat), Wv -> Wv_bf.
__global__ __launch_bounds__(256) void cast_to_bf16(const float* __restrict__ x,
                                                    const float* __restrict__ Wq,
                                                    const float* __restrict__ Wk,
                                                    const float* __restrict__ Wv,
                                                    bf16_t* __restrict__ xb,
                                                    bf16_t* __restrict__ wqk,
                                                    bf16_t* __restrict__ wv) {
    const int NX = (4096 * 1024) / 4;
    const int NW = (1024 * 1024) / 4;
    int idx = blockIdx.x * 256 + threadIdx.x;
    const float* src;
    bf16_t* dst;
    int off;
    if (idx < NX) {
        src = x; dst = xb; off = idx;
    } else if (idx < NX + NW) {
        src = Wq; dst = wqk; off = idx - NX;
    } else if (idx < NX + 2 * NW) {
        src = Wk; dst = wqk + (size_t)NW * 4; off = idx - NX - NW;
    } else {
        src = Wv; dst = wv; off = idx - NX - 2 * NW;
    }
    float4 f = ((const float4*)src)[off];
    bf16x4v o;
    o.x = (bf16_t)f.x; o.y = (bf16_t)f.y; o.z = (bf16_t)f.z; o.w = (bf16_t)f.w;
    *(bf16x4v*)(dst + (size_t)off * 4) = o;
}

extern "C" void kernel_launch(void* const* d_in, const int* in_sizes, int n_in,
                              void* d_out, int out_size, void* d_ws, size_t ws_size,
                              hipStream_t stream) {
    (void)in_sizes; (void)n_in; (void)out_size; (void)ws_size;
    const float* x  = (const float*)d_in[0];
    const float* Wq = (const float*)d_in[1];
    const float* Wk = (const float*)d_in[2];
    const float* Wv = (const float*)d_in[3];
    float* out = (float*)d_out;

    char* ws = (char*)d_ws;
    bf16_t* xb   = (bf16_t*)(ws + (size_t)0);
    bf16_t* wqk  = (bf16_t*)(ws + ((size_t)8 << 20));
    bf16_t* wvb  = (bf16_t*)(ws + ((size_t)12 << 20));
    u8*     qk   = (u8*)(ws + ((size_t)14 << 20));
    bf16_t* vt   = (bf16_t*)(ws + ((size_t)22 << 20));
    bf16_t* P    = (bf16_t*)(ws + ((size_t)30 << 20));
    float* rowsp = (float*)(ws + ((size_t)62 << 20));
    float* parts = (float*)(ws + ((size_t)64 << 20));

    cast_to_bf16<<<7168, 256, 0, stream>>>(x, Wq, Wk, Wv, xb, wqk, wvb);

    // QK (fp8) = x@[Wq;Wk]^T (512 blocks, 2/CU, 1 generation)
    k_qkv<<<512, 256, 0, stream>>>(xb, wqk, qk);

    // Vt (bf16) + P~ = exp((Q@K^T)/32) causal (800 blocks, 4/CU, tail-split)
    k_sv<<<800, 256, 0, stream>>>(xb, wvb, qk, vt, P, rowsp);

    // out = (P~ @ V) * diag(1/rowsum): split-K chunk <=22 (504 blocks, 1 gen)
    k_pv<<<504, 256, 0, stream>>>(P, vt, rowsp, out, parts);
    k_reduce<<<2688, 256, 0, stream>>>(parts, rowsp, out);
}

// Round 11
// 164.680 us; speedup vs baseline: 1.0135x; 1.0044x over previous
//
#include <hip/hip_runtime.h>
#include <hip/hip_bf16.h>

// Causal attention, S=4096, d=1024, fp32 in/out.
// bf16 MFMA for projections and PV; fp8 e4m3 MFMA (BK=128B) for scores only.
//
// Round-21 (this round): k_qkv -> 256x128-tile, 512-thread, counted-ring
// kernel. 256 blocks = 1/CU exact gen; staging traffic -25% (B panels
// amortized over 2x M). LDS 128KB: A ring 3x32KB + B dbuf 2x16KB. Per
// K-step 2 phases x 16 MFMA/wave (8 waves = m201/m218 regime); stage roles
// p1:A1of[kb+2], p2:A2+B[kb+2]; boundary vmcnt(6) counted (never 0 until
// tails); lgkm0+sched_barrier before every barrier (rule 18). QK per-element
// accumulation order unchanged -> absmax canary 0.02734375.
// Everything else frozen at r20 (165.4us).
//
// Workspace (256 MiB):
//   [0,8M)    x_bf  [4096,1024] bf16
//   [8M,12M)  Wqk   [2048,1024] bf16 (Wq rows 0..1023, Wk rows 1024..2047)
//   [12M,14M) Wv_bf [1024,1024] bf16
//   [14M,22M) QK    [4096,2048] fp8  (Q cols 0..1023, K cols 1024..2047)
//   [22M,30M) Vt    [1024,4096] bf16 (V^T, computed directly as Wv @ x^T)
//   [30M,62M) P~    [4096,4096] bf16 (exp(s/32), masked, unnormalized)
//   [62M,62.5M) rowsum_part [4096][32] fp32 (slot bn; dead slots zeroed)
//   [64M,92M) PV fp32 partials (52 multi-split groups x 8 bn x 64 KB)

typedef __bf16 bf16_t;
typedef __bf16 bf16x4v __attribute__((ext_vector_type(4)));
typedef __bf16 bf16x8 __attribute__((ext_vector_type(8)));
typedef float f32x4 __attribute__((ext_vector_type(4)));
typedef unsigned char u8;
typedef long long i64_t;

#define AS1 __attribute__((address_space(1)))
#define AS3 __attribute__((address_space(3)))
#define WAIT_VMCNT(N) asm volatile("s_waitcnt vmcnt(" #N ")" ::: "memory")
#define WAIT_LGKM0() asm volatile("s_waitcnt lgkmcnt(0)" ::: "memory")
#define BARRIER_RAW() asm volatile("s_barrier" ::: "memory")

__device__ __forceinline__ void async_copy16(const void* g, void* l) {
    // 16B/lane direct global->LDS; LDS dest = wave-uniform base + lane*16
    __builtin_amdgcn_global_load_lds((AS1 void*)(g), (AS3 void*)(l), 16, 0, 0);
}

__device__ __forceinline__ u8 f32_to_fp8(float v) {
    // OCP e4m3 on gfx950 (HW conversion); layout validated in round 6
    return (u8)(__builtin_amdgcn_cvt_pk_fp8_f32(v, v, 0, false) & 0xff);
}

__device__ __forceinline__ void store_conv(float* p, float v) { *p = v; }
__device__ __forceinline__ void store_conv(bf16_t* p, float v) { *p = (bf16_t)v; }
__device__ __forceinline__ void store_conv(u8* p, float v) { *p = f32_to_fp8(v); }

// Sum of 32 consecutive floats (8x float4), for 1/rowsum computation.
__device__ __forceinline__ float sum32(const float* p) {
    const f32x4* v = (const f32x4*)p;
    float s = 0.f;
#pragma unroll
    for (int u = 0; u < 8; ++u) {
        f32x4 a = v[u];
        s += a[0] + a[1] + a[2] + a[3];
    }
    return s;
}

// ---------------- bf16 tile: BM=128, BN=128, BK=64 (r12, dbuf 64KB) -------
// Used by k_pv. Double-buffered staging; XOR-swizzled LDS; counted-vmcnt
// 2-barrier K-loop; LDS-bounce epilogue.
// EPI 0: C = v*alpha | EPI 2: C = v * inv[row] (inv indexed by tile-local row)
template <int EPI, typename OutT>
__device__ __forceinline__ void gemm_tile_bf16(const bf16_t* __restrict__ A, int lda,
                                               const bf16_t* __restrict__ B, int ldb,
                                               OutT* __restrict__ C, int ldc,
                                               int kb0, int kb1, float alpha,
                                               char* __restrict__ smem,
                                               const float* __restrict__ inv) {
    constexpr int BK = 64;
    bf16_t* As = (bf16_t*)smem;            // 2 x 8192 elems (16KB each)
    bf16_t* Bs = (bf16_t*)(smem + 32768);  // 2 x 8192 elems
    const int tid = threadIdx.x;
    const int lane = tid & 63, wave = tid >> 6;
    const int wm = wave >> 1, wn = wave & 1;
    const int q = lane >> 4, l16 = lane & 15;

    f32x4 acc[4][4] = {};

    const bf16_t* aSrc[4];
    const bf16_t* bSrc[4];
    int ldsOff[4];
#pragma unroll
    for (int it = 0; it < 4; ++it) {
        int c = it * 256 + tid;
        int r = c >> 3, b = c & 7;
        int sb = b ^ (r & 7);
        aSrc[it] = A + (size_t)r * lda + sb * 8;
        bSrc[it] = B + (size_t)r * ldb + sb * 8;
        ldsOff[it] = c * 8;
    }

    // prologue: stage first K-step into buffer 0 (8 loads in flight)
    {
        const int k0 = kb0 * BK;
#pragma unroll
        for (int it = 0; it < 4; ++it) async_copy16(aSrc[it] + k0, &As[ldsOff[it]]);
#pragma unroll
        for (int it = 0; it < 4; ++it) async_copy16(bSrc[it] + k0, &Bs[ldsOff[it]]);
    }

    int cur = 0;
    for (int kb = kb0; kb < kb1; ++kb) {
        if (kb + 1 < kb1) {  // prefetch next K-step into alternate buffer
            const int k0 = (kb + 1) * BK;
            const int boff = (cur ^ 1) * 8192;
#pragma unroll
            for (int it = 0; it < 4; ++it) async_copy16(aSrc[it] + k0, &As[boff + ldsOff[it]]);
#pragma unroll
            for (int it = 0; it < 4; ++it) async_copy16(bSrc[it] + k0, &Bs[boff + ldsOff[it]]);
            WAIT_VMCNT(8);   // tile-kb loads (8 oldest) retired; kb+1 in flight
        } else {
            WAIT_VMCNT(0);   // tail: drain everything
        }
        __builtin_amdgcn_sched_barrier(0);
        BARRIER_RAW();       // all waves' tile-kb loads landed
        const bf16_t* Ab = As + cur * 8192;
        const bf16_t* Bb = Bs + cur * 8192;
        __builtin_amdgcn_s_setprio(1);
#pragma unroll
        for (int k2 = 0; k2 < 2; ++k2) {
            bf16x8 af[4], bfr[4];
#pragma unroll
            for (int mt = 0; mt < 4; ++mt) {
                int m = wm * 64 + mt * 16 + l16;
                int blk = (k2 * 4 + q) ^ (m & 7);
                af[mt] = *(const bf16x8*)&Ab[m * BK + blk * 8];
            }
#pragma unroll
            for (int nt = 0; nt < 4; ++nt) {
                int nn = wn * 64 + nt * 16 + l16;
                int blk = (k2 * 4 + q) ^ (nn & 7);
                bfr[nt] = *(const bf16x8*)&Bb[nn * BK + blk * 8];
            }
#pragma unroll
            for (int mt = 0; mt < 4; ++mt)
#pragma unroll
                for (int nt = 0; nt < 4; ++nt)
                    acc[mt][nt] = __builtin_amdgcn_mfma_f32_16x16x32_bf16(
                        af[mt], bfr[nt], acc[mt][nt], 0, 0, 0);
        }
        __builtin_amdgcn_s_setprio(0);
        BARRIER_RAW();       // reads of buf done -> next iter may overwrite
        cur ^= 1;
    }

    // Epilogue: bounce C tile (128x128 OutT) through dead staging LDS.
    constexpr int S = (int)sizeof(OutT);
    constexpr int RB = 128 * S;  // bytes per tile row
    const int row0 = wm * 64, col0 = wn * 64;
#pragma unroll
    for (int mt = 0; mt < 4; ++mt)
#pragma unroll
        for (int nt = 0; nt < 4; ++nt)
#pragma unroll
            for (int r = 0; r < 4; ++r) {
                int lr = row0 + mt * 16 + q * 4 + r;
                int lc = col0 + nt * 16 + l16;
                float v = acc[mt][nt][r];
                v = (EPI == 2) ? v * inv[lr] : v * alpha;
                int cb = (lc * S) >> 4;
                int sw = cb ^ ((lr >> 2) & 7);
                store_conv((OutT*)(smem + lr * RB + (sw << 4) + ((lc * S) & 15)), v);
            }
    __syncthreads();
#pragma unroll
    for (int p = 0; p < 4 * S; ++p) {
        int g = p * 4096 + tid * 16;  // linear byte index in tile
        int r = g / RB;
        int wb = g & (RB - 1);
        int sc = (wb >> 4) ^ ((r >> 2) & 7);
        f32x4 val = *(const f32x4*)(smem + r * RB + (sc << 4));
        *(f32x4*)((char*)C + (size_t)r * ((size_t)ldc * S) + wb) = val;
    }
}

// ---------------- bf16 tile, single-buffer 32KB (m97 structure) -----------
__device__ __forceinline__ void gemm_tile_bf16_sb(const bf16_t* __restrict__ A, int lda,
                                                  const bf16_t* __restrict__ B, int ldb,
                                                  bf16_t* __restrict__ C, int ldc,
                                                  int kb1, char* __restrict__ smem) {
    constexpr int BK = 64;
    bf16_t* As = (bf16_t*)smem;            // 8192 elems (16KB)
    bf16_t* Bs = (bf16_t*)(smem + 16384);  // 8192 elems
    const int tid = threadIdx.x;
    const int lane = tid & 63, wave = tid >> 6;
    const int wm = wave >> 1, wn = wave & 1;
    const int q = lane >> 4, l16 = lane & 15;

    f32x4 acc[4][4] = {};

    const bf16_t* aSrc[4];
    const bf16_t* bSrc[4];
    int ldsOff[4];
#pragma unroll
    for (int it = 0; it < 4; ++it) {
        int c = it * 256 + tid;
        int r = c >> 3, b = c & 7;
        int sb = b ^ (r & 7);
        aSrc[it] = A + (size_t)r * lda + sb * 8;
        bSrc[it] = B + (size_t)r * ldb + sb * 8;
        ldsOff[it] = c * 8;
    }

    for (int kb = 0; kb < kb1; ++kb) {
        const int k0 = kb * BK;
#pragma unroll
        for (int it = 0; it < 4; ++it) async_copy16(aSrc[it] + k0, &As[ldsOff[it]]);
#pragma unroll
        for (int it = 0; it < 4; ++it) async_copy16(bSrc[it] + k0, &Bs[ldsOff[it]]);
        __syncthreads();
        __builtin_amdgcn_s_setprio(1);
#pragma unroll
        for (int k2 = 0; k2 < 2; ++k2) {
            bf16x8 af[4], bfr[4];
#pragma unroll
            for (int mt = 0; mt < 4; ++mt) {
                int m = wm * 64 + mt * 16 + l16;
                int blk = (k2 * 4 + q) ^ (m & 7);
                af[mt] = *(const bf16x8*)&As[m * BK + blk * 8];
            }
#pragma unroll
            for (int nt = 0; nt < 4; ++nt) {
                int nn = wn * 64 + nt * 16 + l16;
                int blk = (k2 * 4 + q) ^ (nn & 7);
                bfr[nt] = *(const bf16x8*)&Bs[nn * BK + blk * 8];
            }
#pragma unroll
            for (int mt = 0; mt < 4; ++mt)
#pragma unroll
                for (int nt = 0; nt < 4; ++nt)
                    acc[mt][nt] = __builtin_amdgcn_mfma_f32_16x16x32_bf16(
                        af[mt], bfr[nt], acc[mt][nt], 0, 0, 0);
        }
        __builtin_amdgcn_s_setprio(0);
        __syncthreads();  // reads done -> next stage may overwrite
    }

    // Epilogue: bounce C tile (128x128 bf16, 32KB) through staging LDS.
    constexpr int RB = 256;
    const int row0 = wm * 64, col0 = wn * 64;
#pragma unroll
    for (int mt = 0; mt < 4; ++mt)
#pragma unroll
        for (int nt = 0; nt < 4; ++nt)
#pragma unroll
            for (int r = 0; r < 4; ++r) {
                int lr = row0 + mt * 16 + q * 4 + r;
                int lc = col0 + nt * 16 + l16;
                int cb = (lc * 2) >> 4;
                int sw = cb ^ ((lr >> 2) & 7);
                *(bf16_t*)(smem + lr * RB + (sw << 4) + ((lc * 2) & 15)) =
                    (bf16_t)acc[mt][nt][r];
            }
    __syncthreads();
#pragma unroll
    for (int p = 0; p < 8; ++p) {
        int g = p * 4096 + tid * 16;
        int r = g >> 8, wb = g & 255;
        int sc = (wb >> 4) ^ ((r >> 2) & 7);
        f32x4 val = *(const f32x4*)(smem + r * RB + (sc << 4));
        *(f32x4*)((char*)C + (size_t)r * ((size_t)ldc * 2) + wb) = val;
    }
}

// ---------------- fp8 scores tile, single-buffer 32KB (full 128 rows) -----
__device__ __forceinline__ void scores_tile_fp8_sb(const u8* __restrict__ A, int lda,
                                                   const u8* __restrict__ B, int ldb,
                                                   bf16_t* __restrict__ C, int ldc,
                                                   float alpha, char* __restrict__ smem,
                                                   float* __restrict__ partial,
                                                   int gr0, int gc0) {
    u8* As = (u8*)smem;
    u8* Bs = (u8*)(smem + 16384);
    const int tid = threadIdx.x;
    const int lane = tid & 63, wave = tid >> 6;
    const int wm = wave >> 1, wn = wave & 1;
    const int q = lane >> 4, l16 = lane & 15;

    f32x4 acc[4][4] = {};

    const u8* aSrc[4];
    const u8* bSrc[4];
    int ldsOff[4];
#pragma unroll
    for (int it = 0; it < 4; ++it) {
        int c = it * 256 + tid;
        int r = c >> 3, b = c & 7;
        int sb = b ^ (r & 7);
        aSrc[it] = A + (size_t)r * lda + sb * 16;
        bSrc[it] = B + (size_t)r * ldb + sb * 16;
        ldsOff[it] = c * 16;
    }

    for (int kb = 0; kb < 8; ++kb) {
        const int k0 = kb * 128;
#pragma unroll
        for (int it = 0; it < 4; ++it) async_copy16(aSrc[it] + k0, &As[ldsOff[it]]);
#pragma unroll
        for (int it = 0; it < 4; ++it) async_copy16(bSrc[it] + k0, &Bs[ldsOff[it]]);
        __syncthreads();
        __builtin_amdgcn_s_setprio(1);
#pragma unroll
        for (int k2 = 0; k2 < 4; ++k2) {
            i64_t af[4], bfr[4];
            const int cb = 2 * k2 + (q >> 1), co = (q & 1) * 8;
#pragma unroll
            for (int mt = 0; mt < 4; ++mt) {
                int m = wm * 64 + mt * 16 + l16;
                af[mt] = *(const i64_t*)&As[m * 128 + ((cb ^ (m & 7)) << 4) + co];
            }
#pragma unroll
            for (int nt = 0; nt < 4; ++nt) {
                int nn = wn * 64 + nt * 16 + l16;
                bfr[nt] = *(const i64_t*)&Bs[nn * 128 + ((cb ^ (nn & 7)) << 4) + co];
            }
#pragma unroll
            for (int mt = 0; mt < 4; ++mt)
#pragma unroll
                for (int nt = 0; nt < 4; ++nt)
                    acc[mt][nt] = __builtin_amdgcn_mfma_f32_16x16x32_fp8_fp8(
                        af[mt], bfr[nt], acc[mt][nt], 0, 0, 0);
        }
        __builtin_amdgcn_s_setprio(0);
        __syncthreads();
    }

    // Epilogue: P = exp(v*alpha) masked -> LDS bounce (bf16, 32KB) + per-row
    // sums via 16-lane shfl into sred (smem+32K, disjoint from bounce).
    float* sred = (float*)(smem + 32768);
    const int row0 = wm * 64, col0 = wn * 64;
    float esum[4][4];
#pragma unroll
    for (int mt = 0; mt < 4; ++mt)
#pragma unroll
        for (int r = 0; r < 4; ++r) esum[mt][r] = 0.f;
#pragma unroll
    for (int mt = 0; mt < 4; ++mt)
#pragma unroll
        for (int nt = 0; nt < 4; ++nt)
#pragma unroll
            for (int r = 0; r < 4; ++r) {
                int lr = row0 + mt * 16 + q * 4 + r;
                int lc = col0 + nt * 16 + l16;
                float pe = (gc0 + lc > gr0 + lr) ? 0.f : __expf(acc[mt][nt][r] * alpha);
                esum[mt][r] += pe;
                int sw = (lc >> 3) ^ ((lr >> 2) & 7);
                *(bf16_t*)(smem + lr * 256 + (sw << 4) + ((lc * 2) & 15)) = (bf16_t)pe;
            }
#pragma unroll
    for (int mt = 0; mt < 4; ++mt)
#pragma unroll
        for (int r = 0; r < 4; ++r) {
#pragma unroll
            for (int off = 1; off < 16; off <<= 1)
                esum[mt][r] += __shfl_xor(esum[mt][r], off, 64);
            if (l16 == 0) sred[(row0 + mt * 16 + q * 4 + r) * 2 + wn] = esum[mt][r];
        }
    __syncthreads();
#pragma unroll
    for (int p = 0; p < 8; ++p) {
        int g = p * 4096 + tid * 16;
        int r = g >> 8;
        int wb = g & 255;
        int sc = (wb >> 4) ^ ((r >> 2) & 7);
        f32x4 val = *(const f32x4*)(smem + r * 256 + (sc << 4));
        *(f32x4*)((char*)C + (size_t)r * ((size_t)ldc * 2) + wb) = val;
    }
    if (tid < 128) partial[(size_t)tid * 32] = sred[tid * 2] + sred[tid * 2 + 1];
}

// ---------------- fp8 scores HALF tile (64 Q-rows), tail filler -----------
__device__ __forceinline__ void scores_tile_fp8_sb_half(
        const u8* __restrict__ A, int lda, const u8* __restrict__ B, int ldb,
        bf16_t* __restrict__ C, int ldc, float alpha, char* __restrict__ smem,
        float* __restrict__ partial, int gr0, int gc0, int half) {
    u8* As = (u8*)smem;            // 64 rows x 128B = 8KB used
    u8* Bs = (u8*)(smem + 16384);
    const int tid = threadIdx.x;
    const int lane = tid & 63, wave = tid >> 6;
    const int wm = wave >> 1, wn = wave & 1;
    const int q = lane >> 4, l16 = lane & 15;

    f32x4 acc[2][4] = {};

    const u8* aSrc[2];
    const u8* bSrc[4];
    int aOff[2], bOff[4];
#pragma unroll
    for (int it = 0; it < 2; ++it) {
        int c = it * 256 + tid;
        int r = c >> 3, b = c & 7;      // r = LDS row 0..63
        int sb = b ^ (r & 7);
        int srcRow = r + 32 * half + 32 * it;  // global tile row
        aSrc[it] = A + (size_t)srcRow * lda + sb * 16;
        aOff[it] = c * 16;
    }
#pragma unroll
    for (int it = 0; it < 4; ++it) {
        int c = it * 256 + tid;
        int r = c >> 3, b = c & 7;
        int sb = b ^ (r & 7);
        bSrc[it] = B + (size_t)r * ldb + sb * 16;
        bOff[it] = c * 16;
    }

    for (int kb = 0; kb < 8; ++kb) {
        const int k0 = kb * 128;
#pragma unroll
        for (int it = 0; it < 2; ++it) async_copy16(aSrc[it] + k0, &As[aOff[it]]);
#pragma unroll
        for (int it = 0; it < 4; ++it) async_copy16(bSrc[it] + k0, &Bs[bOff[it]]);
        __syncthreads();
        __builtin_amdgcn_s_setprio(1);
#pragma unroll
        for (int k2 = 0; k2 < 4; ++k2) {
            i64_t af[2], bfr[4];
            const int cb = 2 * k2 + (q >> 1), co = (q & 1) * 8;
#pragma unroll
            for (int mt = 0; mt < 2; ++mt) {
                int m = wm * 32 + mt * 16 + l16;  // As row
                af[mt] = *(const i64_t*)&As[m * 128 + ((cb ^ (m & 7)) << 4) + co];
            }
#pragma unroll
            for (int nt = 0; nt < 4; ++nt) {
                int nn = wn * 64 + nt * 16 + l16;
                bfr[nt] = *(const i64_t*)&Bs[nn * 128 + ((cb ^ (nn & 7)) << 4) + co];
            }
#pragma unroll
            for (int mt = 0; mt < 2; ++mt)
#pragma unroll
                for (int nt = 0; nt < 4; ++nt)
                    acc[mt][nt] = __builtin_amdgcn_mfma_f32_16x16x32_fp8_fp8(
                        af[mt], bfr[nt], acc[mt][nt], 0, 0, 0);
        }
        __builtin_amdgcn_s_setprio(0);
        __syncthreads();
    }

    float* sred = (float*)(smem + 32768);
    const int col0 = wn * 64;
    float esum[2][4];
#pragma unroll
    for (int mt = 0; mt < 2; ++mt)
#pragma unroll
        for (int r = 0; r < 4; ++r) esum[mt][r] = 0.f;
#pragma unroll
    for (int mt = 0; mt < 2; ++mt)
#pragma unroll
        for (int nt = 0; nt < 4; ++nt)
#pragma unroll
            for (int r = 0; r < 4; ++r) {
                int cr = wm * 32 + mt * 16 + q * 4 + r;
                int trow = ((cr >> 5) << 6) + 32 * half + (cr & 31);
                int lc = col0 + nt * 16 + l16;
                float pe = (gc0 + lc > gr0 + trow) ? 0.f : __expf(acc[mt][nt][r] * alpha);
                esum[mt][r] += pe;
                int sw = (lc >> 3) ^ ((cr >> 2) & 7);
                *(bf16_t*)(smem + cr * 256 + (sw << 4) + ((lc * 2) & 15)) = (bf16_t)pe;
            }
#pragma unroll
    for (int mt = 0; mt < 2; ++mt)
#pragma unroll
        for (int r = 0; r < 4; ++r) {
#pragma unroll
            for (int off = 1; off < 16; off <<= 1)
                esum[mt][r] += __shfl_xor(esum[mt][r], off, 64);
            if (l16 == 0)
                sred[(wm * 32 + mt * 16 + q * 4 + r) * 2 + wn] = esum[mt][r];
        }
    __syncthreads();
#pragma unroll
    for (int p = 0; p < 4; ++p) {
        int g = p * 4096 + tid * 16;
        int cr = g >> 8, wb = g & 255;
        int sc = (wb >> 4) ^ ((cr >> 2) & 7);
        f32x4 val = *(const f32x4*)(smem + cr * 256 + (sc << 4));
        int trow = ((cr >> 5) << 6) + 32 * half + (cr & 31);
        *(f32x4*)((char*)C + (size_t)trow * ((size_t)ldc * 2) + wb) = val;
    }
    if (tid < 64) {
        int trow = ((tid >> 5) << 6) + 32 * half + (tid & 31);
        partial[(size_t)trow * 32] = sred[tid * 2] + sred[tid * 2 + 1];
    }
}

// ---------------- QK projection: 256x128 tile, 512 thr, counted ring ------
// 256 blocks (bm 0..15 x bn 0..15) = 1/CU exact generation, 8 waves.
// LDS 128KB: A ring 3 x 32KB (slots kb%3) + B dbuf 2 x 16KB (kb&1).
// Per K-step (BK=64) two phases:
//   p1: ds_read bf(4)+af mh0(8); stage A-part1[kb+2]; lgkm0; bar; 16 MFMA
//   p2: ds_read af mh1(8); stage A-part2[kb+2]+B[kb+2]; lgkm0; 16 MFMA
//   boundary: vmcnt(6) (tails 0); bar.
// Ledger: A[kb+2] issued kb.p1/p2 -> read kb+2 (4-5 phases); B[kb+2] issued
// kb.p2 -> read kb+2.p1 (3 phases). Steady in-flight = 6. Region safety:
// B slot kb&1 dead after p1-barrier (bf in regs); A slot (kb+2)%3 = (kb-1)%3
// dead since kb-1's boundary barrier; all ds_reads drained (lgkm0) before
// each wave's barrier arrival.
// Per-element accumulation order (kb asc, k2 asc) identical to r20 -> QK
// bytes bit-identical -> absmax canary.
__global__ __launch_bounds__(512, 2) void k_qkv(const bf16_t* __restrict__ xb,
                                                const bf16_t* __restrict__ wqk,
                                                u8* __restrict__ qk) {
    __shared__ __attribute__((aligned(16))) char smem[131072];
    const int b = blockIdx.x;
    const int bm = b & 15, bn = b >> 4;  // 16 x 16
    const bf16_t* A = xb + (size_t)bm * 256 * 1024;
    const bf16_t* Bw = wqk + (size_t)bn * 128 * 1024;
    u8* C = qk + (size_t)bm * 256 * 2048 + bn * 128;

    const int tid = threadIdx.x;
    const int lane = tid & 63, wave = tid >> 6;
    const int wm = wave >> 2, wn = wave & 3;   // wm: 128-row half, wn: 32-col
    const int q = lane >> 4, l16 = lane & 15;

    f32x4 acc[8][2] = {};

    // staging sources (pre-swizzled): A 4 passes (rows 0..255), B 2 passes
    const bf16_t* aS[4]; int aO[4];
    const bf16_t* bS[2]; int bO[2];
#pragma unroll
    for (int pp = 0; pp < 4; ++pp) {
        int g = pp * 512 + tid, r = g >> 3, c8 = g & 7, sb = c8 ^ (r & 7);
        aS[pp] = A + (size_t)r * 1024 + sb * 8;
        aO[pp] = g * 16;
    }
#pragma unroll
    for (int pp = 0; pp < 2; ++pp) {
        int g = pp * 512 + tid, r = g >> 3, c8 = g & 7, sb = c8 ^ (r & 7);
        bS[pp] = Bw + (size_t)r * 1024 + sb * 8;
        bO[pp] = g * 16;
    }

    // prologue: stage A,B for kb=0 and kb=1 (12 loads)
#pragma unroll
    for (int kb = 0; kb < 2; ++kb) {
        char* as = smem + kb * 32768;        // kb%3 = kb
        char* bs = smem + 98304 + kb * 16384;
        const int k0 = kb * 64;
        async_copy16(aS[0] + k0, as + aO[0]);
        async_copy16(aS[1] + k0, as + aO[1]);
        async_copy16(aS[2] + k0, as + aO[2]);
        async_copy16(aS[3] + k0, as + aO[3]);
        async_copy16(bS[0] + k0, bs + bO[0]);
        async_copy16(bS[1] + k0, bs + bO[1]);
    }
    WAIT_VMCNT(6);   // kb=0 landed; kb=1's 6 in flight
    __builtin_amdgcn_sched_barrier(0);
    BARRIER_RAW();

    for (int kb = 0; kb < 16; ++kb) {
        const int asl = kb - (kb / 3) * 3;           // kb % 3
        const int nsl = (kb + 2) - ((kb + 2) / 3) * 3;
        const bf16_t* Ab = (const bf16_t*)(smem + asl * 32768);
        const bf16_t* Bb = (const bf16_t*)(smem + 98304 + (kb & 1) * 16384);
        char* nA = smem + nsl * 32768;
        char* nB = smem + 98304 + (kb & 1) * 16384;  // (kb+2)&1 == kb&1
        const int kn = (kb + 2) * 64;
        const bool pre = (kb + 2) < 16;

        bf16x8 bf[2][2], af[4][2];
        // ---- p1: bf all + af mh0; stage A-part1[kb+2]
#pragma unroll
        for (int nt = 0; nt < 2; ++nt)
#pragma unroll
            for (int k2 = 0; k2 < 2; ++k2) {
                int nn = wn * 32 + nt * 16 + l16;
                int blk = (k2 * 4 + q) ^ (nn & 7);
                bf[nt][k2] = *(const bf16x8*)&Bb[nn * 64 + blk * 8];
            }
#pragma unroll
        for (int mt = 0; mt < 4; ++mt)
#pragma unroll
            for (int k2 = 0; k2 < 2; ++k2) {
                int m = wm * 128 + mt * 16 + l16;
                int blk = (k2 * 4 + q) ^ (m & 7);
                af[mt][k2] = *(const bf16x8*)&Ab[m * 64 + blk * 8];
            }
        if (pre) {
            async_copy16(aS[0] + kn, nA + aO[0]);
            async_copy16(aS[1] + kn, nA + aO[1]);
        }
        WAIT_LGKM0();
        __builtin_amdgcn_sched_barrier(0);
        BARRIER_RAW();
        __builtin_amdgcn_s_setprio(1);
#pragma unroll
        for (int mt = 0; mt < 4; ++mt)
#pragma unroll
            for (int nt = 0; nt < 2; ++nt)
#pragma unroll
                for (int k2 = 0; k2 < 2; ++k2)
                    acc[mt][nt] = __builtin_amdgcn_mfma_f32_16x16x32_bf16(
                        af[mt][k2], bf[nt][k2], acc[mt][nt], 0, 0, 0);
        __builtin_amdgcn_s_setprio(0);

        // ---- p2: af mh1; stage A-part2[kb+2] + B[kb+2]
#pragma unroll
        for (int mt = 0; mt < 4; ++mt)
#pragma unroll
            for (int k2 = 0; k2 < 2; ++k2) {
                int m = wm * 128 + (4 + mt) * 16 + l16;
                int blk = (k2 * 4 + q) ^ (m & 7);
                af[mt][k2] = *(const bf16x8*)&Ab[m * 64 + blk * 8];
            }
        if (pre) {
            async_copy16(aS[2] + kn, nA + aO[2]);
            async_copy16(aS[3] + kn, nA + aO[3]);
            async_copy16(bS[0] + kn, nB + bO[0]);
            async_copy16(bS[1] + kn, nB + bO[1]);
        }
        WAIT_LGKM0();
        __builtin_amdgcn_sched_barrier(0);
        __builtin_amdgcn_s_setprio(1);
#pragma unroll
        for (int mt = 0; mt < 4; ++mt)
#pragma unroll
            for (int nt = 0; nt < 2; ++nt)
#pragma unroll
                for (int k2 = 0; k2 < 2; ++k2)
                    acc[4 + mt][nt] = __builtin_amdgcn_mfma_f32_16x16x32_bf16(
                        af[mt][k2], bf[nt][k2], acc[4 + mt][nt], 0, 0, 0);
        __builtin_amdgcn_s_setprio(0);

        // ---- boundary
        if (pre) { WAIT_VMCNT(6); } else { WAIT_VMCNT(0); }
        __builtin_amdgcn_sched_barrier(0);
        BARRIER_RAW();
    }

    // Epilogue: fp8 convert -> 32KB bounce (u8 256x128) -> coalesced stores.
#pragma unroll
    for (int mt = 0; mt < 8; ++mt)
#pragma unroll
        for (int nt = 0; nt < 2; ++nt)
#pragma unroll
            for (int r = 0; r < 4; ++r) {
                int lr = wm * 128 + mt * 16 + q * 4 + r;
                int lc = wn * 32 + nt * 16 + l16;
                int cb = lc >> 4;
                int sw = cb ^ ((lr >> 2) & 7);
                *(u8*)(smem + lr * 128 + (sw << 4) + (lc & 15)) =
                    f32_to_fp8(acc[mt][nt][r]);
            }
    __syncthreads();
#pragma unroll
    for (int p = 0; p < 4; ++p) {
        int g = p * 8192 + tid * 16;
        int r = g >> 7, wb = g & 127;
        int sc = (wb >> 4) ^ ((r >> 2) & 7);
        f32x4 val = *(const f32x4*)(smem + r * 128 + (sc << 4));
        *(f32x4*)((char*)C + (size_t)r * 2048 + wb) = val;
    }
}

// Merged dispatch, 800 blocks @ 33KB LDS + launch_bounds(256,4) = 4/CU:
//   b in [0,256): Vt; [256,768): full score tiles; [768,800): half tiles.
__global__ __launch_bounds__(256, 4) void k_sv(const bf16_t* __restrict__ xb,
                                               const bf16_t* __restrict__ wvb,
                                               const u8* __restrict__ qk,
                                               bf16_t* __restrict__ vt,
                                               bf16_t* __restrict__ P,
                                               float* __restrict__ rowsum_part) {
    __shared__ __attribute__((aligned(16))) char smem[33792];
    int b = blockIdx.x;
    if (b < 256) {
        int bm = b & 7, bn = b >> 3;  // bn 0..31
        gemm_tile_bf16_sb(wvb + (size_t)bm * 128 * 1024, 1024,
                          xb + (size_t)bn * 128 * 1024, 1024,
                          vt + (size_t)bm * 128 * 4096 + bn * 128, 4096,
                          16, smem);
        return;
    }
    if (b < 768) {
        int t = b - 256;  // 0..511 (tiles (31,16..31) excluded -> halves)
        int bm = (int)((sqrtf(8.f * (float)t + 1.f) - 1.f) * 0.5f);
        while (bm * (bm + 1) / 2 > t) --bm;
        while ((bm + 1) * (bm + 2) / 2 <= t) ++bm;
        int bn = t - bm * (bm + 1) / 2;  // 0..bm
        scores_tile_fp8_sb(qk + (size_t)bm * 128 * 2048, 2048,
                           qk + 1024 + (size_t)bn * 128 * 2048, 2048,
                           P + (size_t)bm * 128 * 4096 + bn * 128, 4096,
                           0.03125f, smem,
                           rowsum_part + (size_t)bm * 128 * 32 + bn,
                           bm * 128, bn * 128);
        if (bn == bm) {  // zero dead rowsum slots for this row block
            float* rp = rowsum_part + (size_t)bm * 128 * 32;
            int tid = threadIdx.x;
            for (int r = tid >> 4; r < 128; r += 16)
                for (int u = bm + 1 + (tid & 15); u < 32; u += 16)
                    rp[r * 32 + u] = 0.f;
        }
        return;
    }
    int j = b - 768;  // 0..31
    int bn = 16 + (j >> 1);
    int half = j & 1;
    scores_tile_fp8_sb_half(qk + (size_t)31 * 128 * 2048, 2048,
                            qk + 1024 + (size_t)bn * 128 * 2048, 2048,
                            P + (size_t)31 * 128 * 4096 + bn * 128, 4096,
                            0.03125f, smem,
                            rowsum_part + (size_t)31 * 128 * 32 + bn,
                            31 * 128, bn * 128, half);
}

// O = (P~ @ V) * diag(1/rowsum), bf16, BK=64: nk = 2(bm+1) iters.
// Split-K chunk <=22 (r16 config, proven): 504 blocks, 1 gen at 2/CU.
__global__ __launch_bounds__(256) void k_pv(const bf16_t* __restrict__ P,
                                            const bf16_t* __restrict__ vt,
                                            const float* __restrict__ rowsum_part,
                                            float* __restrict__ out,
                                            float* __restrict__ partials) {
    __shared__ __attribute__((aligned(16))) char smem[65536];
    __shared__ float sInv[128];
    int b = blockIdx.x;
    int bn = b & 7, g = b >> 3;  // g 0..62
    int bm, s, ns;
    if (g < 11)      { bm = g;                  s = 0;             ns = 1; }
    else if (g < 33) { bm = 11 + (g - 11) / 2;  s = (g - 11) % 2;  ns = 2; }
    else             { bm = 22 + (g - 33) / 3;  s = (g - 33) % 3;  ns = 3; }
    int nk = 2 * (bm + 1);
    int kb0 = s * nk / ns;
    int kb1 = (s + 1) * nk / ns;

    const bf16_t* A = P + (size_t)bm * 128 * 4096;
    const bf16_t* B = vt + (size_t)bn * 128 * 4096;
    if (ns == 1) {
        int tid = threadIdx.x;
        if (tid < 128)
            sInv[tid] = 1.f / sum32(rowsum_part + (size_t)(bm * 128 + tid) * 32);
        // visibility of sInv covered by the K-loop's first barrier
        gemm_tile_bf16<2, float>(A, 4096, B, 4096,
                                 out + (size_t)bm * 128 * 1024 + bn * 128, 1024,
                                 kb0, kb1, 1.f, smem, sInv);
    } else {
        int cum = (bm < 22) ? (bm - 11) * 2 : 22 + (bm - 22) * 3;
        gemm_tile_bf16<0, float>(A, 4096, B, 4096,
                                 partials + ((size_t)(cum + s) * 8 + bn) * 16384, 128,
                                 kb0, kb1, 1.f, smem, nullptr);
    }
}

// out tiles for bm in [11,31]: sum 2..3 fp32 partials, scale by 1/rowsum.
__global__ __launch_bounds__(256) void k_reduce(const float* __restrict__ partials,
                                                const float* __restrict__ rowsum_part,
                                                float* __restrict__ out) {
    int b = blockIdx.x;
    int t = b % 168, p = b / 168;
    int bm = 11 + t % 21, bn = t / 21;
    int ns = (bm < 22) ? 2 : 3;
    int cum = (bm < 22) ? (bm - 11) * 2 : 22 + (bm - 22) * 3;
    __shared__ float sInv[8];
    int tid = threadIdx.x;
    if (tid < 8) {
        int row = bm * 128 + p * 8 + tid;
        sInv[tid] = 1.f / sum32(rowsum_part + (size_t)row * 32);
    }
    __syncthreads();

    int idx = p * 1024 + tid * 4;
    int lr = idx >> 7, lc = idx & 127;
    float sx = 0.f, sy = 0.f, sz = 0.f, sw = 0.f;
    for (int u = 0; u < ns; ++u) {
        const float4 v = *(const float4*)(partials + ((size_t)(cum + u) * 8 + bn) * 16384 + idx);
        sx += v.x; sy += v.y; sz += v.z; sw += v.w;
    }
    float inv = sInv[lr - p * 8];
    float4 o = {sx * inv, sy * inv, sz * inv, sw * inv};
    *(float4*)(out + (size_t)(bm * 128 + lr) * 1024 + bn * 128 + lc) = o;
}

// fp32 -> bf16 casts: x -> x_bf, Wq|Wk -> Wqk (concat), Wv -> Wv_bf.
__global__ __launch_bounds__(256) void cast_to_bf16(const float* __restrict__ x,
                                                    const float* __restrict__ Wq,
                                                    const float* __restrict__ Wk,
                                                    const float* __restrict__ Wv,
                                                    bf16_t* __restrict__ xb,
                                                    bf16_t* __restrict__ wqk,
                                                    bf16_t* __restrict__ wv) {
    const int NX = (4096 * 1024) / 4;
    const int NW = (1024 * 1024) / 4;
    int idx = blockIdx.x * 256 + threadIdx.x;
    const float* src;
    bf16_t* dst;
    int off;
    if (idx < NX) {
        src = x; dst = xb; off = idx;
    } else if (idx < NX + NW) {
        src = Wq; dst = wqk; off = idx - NX;
    } else if (idx < NX + 2 * NW) {
        src = Wk; dst = wqk + (size_t)NW * 4; off = idx - NX - NW;
    } else {
        src = Wv; dst = wv; off = idx - NX - 2 * NW;
    }
    float4 f = ((const float4*)src)[off];
    bf16x4v o;
    o.x = (bf16_t)f.x; o.y = (bf16_t)f.y; o.z = (bf16_t)f.z; o.w = (bf16_t)f.w;
    *(bf16x4v*)(dst + (size_t)off * 4) = o;
}

extern "C" void kernel_launch(void* const* d_in, const int* in_sizes, int n_in,
                              void* d_out, int out_size, void* d_ws, size_t ws_size,
                              hipStream_t stream) {
    (void)in_sizes; (void)n_in; (void)out_size; (void)ws_size;
    const float* x  = (const float*)d_in[0];
    const float* Wq = (const float*)d_in[1];
    const float* Wk = (const float*)d_in[2];
    const float* Wv = (const float*)d_in[3];
    float* out = (float*)d_out;

    char* ws = (char*)d_ws;
    bf16_t* xb   = (bf16_t*)(ws + (size_t)0);
    bf16_t* wqk  = (bf16_t*)(ws + ((size_t)8 << 20));
    bf16_t* wvb  = (bf16_t*)(ws + ((size_t)12 << 20));
    u8*     qk   = (u8*)(ws + ((size_t)14 << 20));
    bf16_t* vt   = (bf16_t*)(ws + ((size_t)22 << 20));
    bf16_t* P    = (bf16_t*)(ws + ((size_t)30 << 20));
    float* rowsp = (float*)(ws + ((size_t)62 << 20));
    float* parts = (float*)(ws + ((size_t)64 << 20));

    cast_to_bf16<<<7168, 256, 0, stream>>>(x, Wq, Wk, Wv, xb, wqk, wvb);

    // QK (fp8) = x@[Wq;Wk]^T (256 blocks, 512 thr, 1/CU, counted ring)
    k_qkv<<<256, 512, 0, stream>>>(xb, wqk, qk);

    // Vt (bf16) + P~ = exp((Q@K^T)/32) causal (800 blocks, 4/CU, tail-split)
    k_sv<<<800, 256, 0, stream>>>(xb, wvb, qk, vt, P, rowsp);

    // out = (P~ @ V) * diag(1/rowsum): split-K chunk <=22 (504 blocks, 1 gen)
    k_pv<<<504, 256, 0, stream>>>(P, vt, rowsp, out, parts);
    k_reduce<<<2688, 256, 0, stream>>>(parts, rowsp, out);
}